// Round 1
// baseline (1325.228 us; speedup 1.0000x reference)
//
#include <hip/hip_runtime.h>
#include <math.h>

// Problem constants (from reference)
#define E_N     7
#define BATCH   32768
#define STATE_D 32
#define ACT_D   8
#define D0      40      // STATE+ACTION
#define D1      256
#define D2      256
#define D3      256
#define D4      128
#define DOUT    32

#define TILE_B  64
#define THREADS 256
#define LDH     260     // padded stride (floats) for h tile: 260%32=4 -> 2-way bank alias (free)
#define LDX     44      // padded stride for x tile

__device__ __forceinline__ float f4c(const float4& v, int i) {
    return reinterpret_cast<const float*>(&v)[i];
}

__device__ __forceinline__ float swish_f(float x) {
    // x * sigmoid(x); v_exp + v_rcp, rel err ~1e-6 vs fp32 ref
    float t = __expf(-x);
    return x * __builtin_amdgcn_rcpf(1.0f + t);
}

__device__ __forceinline__ float softplus_f(float z) {
    // stable: large z -> z; else log1p(exp(z))
    return (z > 20.0f) ? z : log1pf(expf(z));
}

__device__ __forceinline__ float soft_clamp_f(float x, float mn, float mx) {
    x = mx - softplus_f(mx - x);
    x = mn + softplus_f(x - mn);
    return x;
}

// Generic fused layer: lout[64][N] = act(lin[64][K] @ W[K][N] + bias)
// Thread (tx,ty): rows ty*4..ty*4+3, cols {jj*64 + tx*4 .. +3} for jj<N/64.
// Safe in-place (lin==lout): all reads happen before the barrier, writes after.
template<int K, int N, int LDIN, bool SW>
__device__ __forceinline__ void layer_fn(const float* __restrict__ lin,
                                         float* __restrict__ lout,
                                         const float* __restrict__ W,
                                         const float* __restrict__ bias,
                                         int tx, int ty)
{
    constexpr int CH = N / 64;       // float4 chunks per thread (4,4,4,2)
    float4 acc[4][CH];
    #pragma unroll
    for (int jj = 0; jj < CH; ++jj) {
        float4 bv = *reinterpret_cast<const float4*>(&bias[jj*64 + tx*4]);
        #pragma unroll
        for (int r = 0; r < 4; ++r) acc[r][jj] = bv;
    }

    for (int k0 = 0; k0 < K; k0 += 4) {
        float4 a[4];
        #pragma unroll
        for (int r = 0; r < 4; ++r)
            a[r] = *reinterpret_cast<const float4*>(&lin[(ty*4 + r)*LDIN + k0]);
        #pragma unroll
        for (int kk = 0; kk < 4; ++kk) {
            float4 w[CH];
            #pragma unroll
            for (int jj = 0; jj < CH; ++jj)
                w[jj] = *reinterpret_cast<const float4*>(&W[(k0+kk)*N + jj*64 + tx*4]);
            #pragma unroll
            for (int r = 0; r < 4; ++r) {
                float av = f4c(a[r], kk);
                #pragma unroll
                for (int jj = 0; jj < CH; ++jj) {
                    acc[r][jj].x = fmaf(av, w[jj].x, acc[r][jj].x);
                    acc[r][jj].y = fmaf(av, w[jj].y, acc[r][jj].y);
                    acc[r][jj].z = fmaf(av, w[jj].z, acc[r][jj].z);
                    acc[r][jj].w = fmaf(av, w[jj].w, acc[r][jj].w);
                }
            }
        }
    }
    __syncthreads();   // all reads of lin done
    #pragma unroll
    for (int r = 0; r < 4; ++r) {
        #pragma unroll
        for (int jj = 0; jj < CH; ++jj) {
            float4 v = acc[r][jj];
            if (SW) {
                v.x = swish_f(v.x); v.y = swish_f(v.y);
                v.z = swish_f(v.z); v.w = swish_f(v.w);
            }
            *reinterpret_cast<float4*>(&lout[(ty*4 + r)*LDH + jj*64 + tx*4]) = v;
        }
    }
    __syncthreads();   // lout ready for next layer
}

__global__ __launch_bounds__(THREADS, 2)
void ens_fwd(const float* __restrict__ g_state, const float* __restrict__ g_action,
             const float* __restrict__ W0, const float* __restrict__ b0,
             const float* __restrict__ W1, const float* __restrict__ b1,
             const float* __restrict__ W2, const float* __restrict__ b2,
             const float* __restrict__ W3, const float* __restrict__ b3,
             const float* __restrict__ Wmu, const float* __restrict__ bmu,
             const float* __restrict__ Wsg, const float* __restrict__ bsg,
             const float* __restrict__ mxl, const float* __restrict__ mnl,
             float* __restrict__ out)
{
    __shared__ float h[TILE_B * LDH];   // 66.5 KB
    __shared__ float xb[TILE_B * LDX];  // 11.3 KB  (total 77.8 KB -> 2 blocks/CU)

    const int tid  = threadIdx.x;
    const int tx   = tid & 15;
    const int ty   = tid >> 4;
    const int e    = blockIdx.x / (BATCH / TILE_B);
    const int brow0 = (blockIdx.x % (BATCH / TILE_B)) * TILE_B;

    // Stage x = [state | action] tile into LDS (coalesced float4)
    for (int i = tid; i < TILE_B * 8; i += THREADS) {
        int r = i >> 3, c = (i & 7) << 2;
        *reinterpret_cast<float4*>(&xb[r*LDX + c]) =
            *reinterpret_cast<const float4*>(&g_state[(size_t)(brow0 + r)*STATE_D + c]);
    }
    if (tid < TILE_B * 2) {
        int r = tid >> 1, c = (tid & 1) << 2;
        *reinterpret_cast<float4*>(&xb[r*LDX + STATE_D + c]) =
            *reinterpret_cast<const float4*>(&g_action[(size_t)(brow0 + r)*ACT_D + c]);
    }
    __syncthreads();

    layer_fn<D0, D1, LDX, true>(xb, h, W0 + e*D0*D1, b0 + e*D1, tx, ty);
    layer_fn<D1, D2, LDH, true>(h,  h, W1 + e*D1*D2, b1 + e*D2, tx, ty);
    layer_fn<D2, D3, LDH, true>(h,  h, W2 + e*D2*D3, b2 + e*D3, tx, ty);
    layer_fn<D3, D4, LDH, true>(h,  h, W3 + e*D3*D4, b3 + e*D4, tx, ty);

    // ---- Heads: mu and log_sigma, each [64][32]; thread: 4 rows x 2 cols ----
    const float* Wm = Wmu + e*D4*DOUT;
    const float* Ws = Wsg + e*D4*DOUT;
    float2 am[4], as[4];
    {
        float2 bm = *reinterpret_cast<const float2*>(&bmu[e*DOUT + tx*2]);
        float2 bs = *reinterpret_cast<const float2*>(&bsg[e*DOUT + tx*2]);
        #pragma unroll
        for (int r = 0; r < 4; ++r) { am[r] = bm; as[r] = bs; }
    }
    for (int k0 = 0; k0 < D4; k0 += 4) {
        float4 a[4];
        #pragma unroll
        for (int r = 0; r < 4; ++r)
            a[r] = *reinterpret_cast<const float4*>(&h[(ty*4 + r)*LDH + k0]);
        #pragma unroll
        for (int kk = 0; kk < 4; ++kk) {
            float2 wm = *reinterpret_cast<const float2*>(&Wm[(k0+kk)*DOUT + tx*2]);
            float2 ws = *reinterpret_cast<const float2*>(&Ws[(k0+kk)*DOUT + tx*2]);
            #pragma unroll
            for (int r = 0; r < 4; ++r) {
                float av = f4c(a[r], kk);
                am[r].x = fmaf(av, wm.x, am[r].x);
                am[r].y = fmaf(av, wm.y, am[r].y);
                as[r].x = fmaf(av, ws.x, as[r].x);
                as[r].y = fmaf(av, ws.y, as[r].y);
            }
        }
    }
    const float2 mx = *reinterpret_cast<const float2*>(&mxl[tx*2]);
    const float2 mn = *reinterpret_cast<const float2*>(&mnl[tx*2]);
    #pragma unroll
    for (int r = 0; r < 4; ++r) {
        const int row = brow0 + ty*4 + r;
        float2 st = *reinterpret_cast<const float2*>(&g_state[(size_t)row*STATE_D + tx*2]);
        float2 mu;
        mu.x = am[r].x + st.x;
        mu.y = am[r].y + st.y;
        float2 sg;
        sg.x = expf(soft_clamp_f(as[r].x, mn.x, mx.x));
        sg.y = expf(soft_clamp_f(as[r].y, mn.y, mx.y));
        size_t idx = ((size_t)e*BATCH + row)*DOUT + tx*2;
        *reinterpret_cast<float2*>(&out[idx]) = mu;
        *reinterpret_cast<float2*>(&out[(size_t)E_N*BATCH*DOUT + idx]) = sg;
    }
}

extern "C" void kernel_launch(void* const* d_in, const int* in_sizes, int n_in,
                              void* d_out, int out_size, void* d_ws, size_t ws_size,
                              hipStream_t stream) {
    (void)in_sizes; (void)n_in; (void)out_size; (void)d_ws; (void)ws_size;
    const float* state  = (const float*)d_in[0];
    const float* action = (const float*)d_in[1];
    const float* W0  = (const float*)d_in[2];
    const float* b0  = (const float*)d_in[3];
    const float* W1  = (const float*)d_in[4];
    const float* b1  = (const float*)d_in[5];
    const float* W2  = (const float*)d_in[6];
    const float* b2  = (const float*)d_in[7];
    const float* W3  = (const float*)d_in[8];
    const float* b3  = (const float*)d_in[9];
    const float* Wmu = (const float*)d_in[10];
    const float* bmu = (const float*)d_in[11];
    const float* Wsg = (const float*)d_in[12];
    const float* bsg = (const float*)d_in[13];
    const float* mxl = (const float*)d_in[14];
    const float* mnl = (const float*)d_in[15];
    float* out = (float*)d_out;

    dim3 grid(E_N * (BATCH / TILE_B));
    dim3 block(THREADS);
    ens_fwd<<<grid, block, 0, stream>>>(state, action, W0, b0, W1, b1, W2, b2,
                                        W3, b3, Wmu, bmu, Wsg, bsg, mxl, mnl, out);
}

// Round 2
// 554.115 us; speedup vs baseline: 2.3916x; 2.3916x over previous
//
#include <hip/hip_runtime.h>
#include <math.h>
#include <stdint.h>

// ---------------- Problem constants ----------------
#define E_N     7
#define BATCH   32768
#define STATE_D 32
#define ACT_D   8
#define D1      256
#define D4      128
#define DOUT    32

typedef __bf16 bf16;
typedef __attribute__((ext_vector_type(8))) __bf16  bf16x8;
typedef __attribute__((ext_vector_type(4))) float   f32x4;

// ---------------- ws layout (elements of unsigned short) ----------------
// Per-layer weight arrays, transposed to [E][N][Kpad], split hi/lo bf16.
#define SZ0   114688    // 7*256*64
#define SZ1   458752    // 7*256*256
#define SZ3   229376    // 7*128*256
#define SZH   57344     // 7*64*128
#define OFF0H 0
#define OFF0L (OFF0H+SZ0)
#define OFF1H (OFF0L+SZ0)
#define OFF1L (OFF1H+SZ1)
#define OFF2H (OFF1L+SZ1)
#define OFF2L (OFF2H+SZ1)
#define OFF3H (OFF2L+SZ1)
#define OFF3L (OFF3H+SZ3)
#define OFFHH (OFF3L+SZ3)
#define OFFHL (OFFHH+SZH)
#define WS_ELEMS (OFFHL+SZH)          // 2,637,824
#define WS_BYTES ((size_t)WS_ELEMS*2) // 5,275,648

// ---------------- common math ----------------
__device__ __forceinline__ float swish_f(float x) {
    float t = __expf(-x);
    return x * __builtin_amdgcn_rcpf(1.0f + t);
}
__device__ __forceinline__ float softplus_f(float z) {
    return (z > 20.0f) ? z : log1pf(expf(z));
}
__device__ __forceinline__ float soft_clamp_f(float x, float mn, float mx) {
    x = mx - softplus_f(mx - x);
    x = mn + softplus_f(x - mn);
    return x;
}

// ============================================================================
// Prep: split+transpose weights into bf16 hi/lo fragment-order arrays in ws.
// Output layouts: L0 [7][256][64] (k 40..63 zero-pad), L1/L2 [7][256][256],
// L3 [7][128][256], Heads [7][64][128] (n<32 = Wmu col n, n>=32 = Wsig col n-32)
// ============================================================================
#define PREP_N 1318912
__global__ __launch_bounds__(256) void prep_w(
    const float* __restrict__ W0, const float* __restrict__ W1,
    const float* __restrict__ W2, const float* __restrict__ W3,
    const float* __restrict__ Wmu, const float* __restrict__ Wsg,
    unsigned short* __restrict__ ws)
{
    int idx = blockIdx.x * 256 + threadIdx.x;
    if (idx >= PREP_N) return;
    float w;
    int oh, ol;
    if (idx < SZ0) {                       // L0
        int e = idx >> 14, r = idx & 16383, n = r >> 6, k = r & 63;
        w = (k < 40) ? W0[(e*40 + k)*256 + n] : 0.0f;
        oh = OFF0H + idx; ol = OFF0L + idx;
    } else if (idx < SZ0 + SZ1) {          // L1
        int t = idx - SZ0;
        int e = t >> 16, r = t & 65535, n = r >> 8, k = r & 255;
        w = W1[(e<<16) + (k<<8) + n];
        oh = OFF1H + t; ol = OFF1L + t;
    } else if (idx < SZ0 + 2*SZ1) {        // L2
        int t = idx - (SZ0 + SZ1);
        int e = t >> 16, r = t & 65535, n = r >> 8, k = r & 255;
        w = W2[(e<<16) + (k<<8) + n];
        oh = OFF2H + t; ol = OFF2L + t;
    } else if (idx < SZ0 + 2*SZ1 + SZ3) {  // L3 [E][128][256] from W3 [E][256][128]
        int t = idx - (SZ0 + 2*SZ1);
        int e = t >> 15, r = t & 32767, n = r >> 8, k = r & 255;
        w = W3[(e<<15) + (k<<7) + n];
        oh = OFF3H + t; ol = OFF3L + t;
    } else {                               // Heads [E][64][128]
        int t = idx - (SZ0 + 2*SZ1 + SZ3);
        int e = t >> 13, r = t & 8191, n = r >> 7, k = r & 127;
        w = (n < 32) ? Wmu[(e<<12) + (k<<5) + n]
                     : Wsg[(e<<12) + (k<<5) + (n-32)];
        oh = OFFHH + t; ol = OFFHL + t;
    }
    bf16 hi = (bf16)w;
    bf16 lo = (bf16)(w - (float)hi);
    ws[oh] = __builtin_bit_cast(unsigned short, hi);
    ws[ol] = __builtin_bit_cast(unsigned short, lo);
}

// ============================================================================
// Main fused MFMA kernel. Block = 512 thr (8 waves), 64 batch rows.
// LDS: h hi/lo [64][256] bf16 (stride 256) + x hi/lo [64][64] = 80 KB.
// XOR swizzle: elem_col ^= (row&7)<<3   (16B granule spread over 8 banks-slots)
// ============================================================================
template<int KT, int MT, int NTW, int KPAD, int ASTR>
__device__ __forceinline__ void layer_mm(
    const unsigned short* __restrict__ Whi, const unsigned short* __restrict__ Wlo,
    const float* __restrict__ bias,
    const unsigned short* aH, const unsigned short* aL,
    unsigned short* dH, unsigned short* dL,
    int ntile0, int lane)
{
    const int ln = lane & 15, lg = lane >> 4, l7 = lane & 7;
    f32x4 acc[MT][NTW];
    int nidx[NTW];
    #pragma unroll
    for (int j = 0; j < NTW; ++j) {
        nidx[j] = (ntile0 + j)*16 + ln;
        float bv = bias[nidx[j]];
        #pragma unroll
        for (int mt = 0; mt < MT; ++mt) acc[mt][j] = (f32x4){bv, bv, bv, bv};
    }
    #pragma unroll 2
    for (int kt = 0; kt < KT; ++kt) {
        const int kcol = kt*32 + lg*8;
        bf16x8 bh[NTW], bl[NTW];
        #pragma unroll
        for (int j = 0; j < NTW; ++j) {
            int off = nidx[j]*KPAD + kcol;
            bh[j] = *reinterpret_cast<const bf16x8*>(&Whi[off]);
            bl[j] = *reinterpret_cast<const bf16x8*>(&Wlo[off]);
        }
        #pragma unroll
        for (int mt = 0; mt < MT; ++mt) {
            int row = mt*16 + ln;
            int ae  = row*ASTR + (kcol ^ (l7 << 3));
            bf16x8 ah = *reinterpret_cast<const bf16x8*>(&aH[ae]);
            bf16x8 al = *reinterpret_cast<const bf16x8*>(&aL[ae]);
            #pragma unroll
            for (int j = 0; j < NTW; ++j) {
                acc[mt][j] = __builtin_amdgcn_mfma_f32_16x16x32_bf16(ah, bh[j], acc[mt][j], 0, 0, 0);
                acc[mt][j] = __builtin_amdgcn_mfma_f32_16x16x32_bf16(ah, bl[j], acc[mt][j], 0, 0, 0);
                acc[mt][j] = __builtin_amdgcn_mfma_f32_16x16x32_bf16(al, bh[j], acc[mt][j], 0, 0, 0);
            }
        }
    }
    __syncthreads();   // all A reads done -> safe to overwrite in place
    #pragma unroll
    for (int mt = 0; mt < MT; ++mt) {
        #pragma unroll
        for (int r = 0; r < 4; ++r) {
            int row = mt*16 + lg*4 + r;
            int sw  = (row & 7) << 3;
            #pragma unroll
            for (int j = 0; j < NTW; ++j) {
                float v = acc[mt][j][r];
                v = swish_f(v);
                bf16 hi = (bf16)v;
                bf16 lo = (bf16)(v - (float)hi);
                int de = row*256 + (nidx[j] ^ sw);
                dH[de] = __builtin_bit_cast(unsigned short, hi);
                dL[de] = __builtin_bit_cast(unsigned short, lo);
            }
        }
    }
    __syncthreads();   // writes visible to all waves
}

__global__ __launch_bounds__(512, 4) void ens_mfma(
    const float* __restrict__ gs, const float* __restrict__ ga,
    const unsigned short* __restrict__ ws,
    const float* __restrict__ b0, const float* __restrict__ b1,
    const float* __restrict__ b2, const float* __restrict__ b3,
    const float* __restrict__ bmu, const float* __restrict__ bsg,
    const float* __restrict__ mxl, const float* __restrict__ mnl,
    float* __restrict__ out)
{
    __shared__ unsigned short hH[64*256], hL[64*256], xH[64*64], xL[64*64];

    const int tid  = threadIdx.x;
    const int lane = tid & 63, wv = tid >> 6;
    const int ln = lane & 15, lg = lane >> 4, l7 = lane & 7;
    const int e = blockIdx.x >> 9;
    const int brow0 = (blockIdx.x & 511) << 6;

    // ---- stage x = [state | action | 0-pad] as hi/lo bf16, swizzled ----
    {
        int row = tid >> 3, ch = tid & 7, kb = ch << 3;
        float v[8];
        if (ch < 4) {
            float4 a = *reinterpret_cast<const float4*>(&gs[(size_t)(brow0+row)*32 + kb]);
            float4 b = *reinterpret_cast<const float4*>(&gs[(size_t)(brow0+row)*32 + kb + 4]);
            v[0]=a.x; v[1]=a.y; v[2]=a.z; v[3]=a.w; v[4]=b.x; v[5]=b.y; v[6]=b.z; v[7]=b.w;
        } else if (ch == 4) {
            float4 a = *reinterpret_cast<const float4*>(&ga[(size_t)(brow0+row)*8]);
            float4 b = *reinterpret_cast<const float4*>(&ga[(size_t)(brow0+row)*8 + 4]);
            v[0]=a.x; v[1]=a.y; v[2]=a.z; v[3]=a.w; v[4]=b.x; v[5]=b.y; v[6]=b.z; v[7]=b.w;
        } else {
            #pragma unroll
            for (int i = 0; i < 8; ++i) v[i] = 0.0f;
        }
        int sw = (row & 7) << 3;
        #pragma unroll
        for (int p = 0; p < 4; ++p) {
            int k  = kb + p*2;
            int el = row*64 + (k ^ sw);
            bf16 h0 = (bf16)v[2*p],   h1 = (bf16)v[2*p+1];
            bf16 l0 = (bf16)(v[2*p]   - (float)h0);
            bf16 l1 = (bf16)(v[2*p+1] - (float)h1);
            *reinterpret_cast<uint32_t*>(&xH[el]) =
                ((uint32_t)__builtin_bit_cast(unsigned short, h1) << 16) |
                 (uint32_t)__builtin_bit_cast(unsigned short, h0);
            *reinterpret_cast<uint32_t*>(&xL[el]) =
                ((uint32_t)__builtin_bit_cast(unsigned short, l1) << 16) |
                 (uint32_t)__builtin_bit_cast(unsigned short, l0);
        }
    }
    __syncthreads();

    // ---- layer chain ----
    layer_mm<2,4,2, 64, 64>(ws + OFF0H + e*16384, ws + OFF0L + e*16384,
                            b0 + e*256, xH, xL, hH, hL, wv*2, lane);
    layer_mm<8,4,2,256,256>(ws + OFF1H + e*65536, ws + OFF1L + e*65536,
                            b1 + e*256, hH, hL, hH, hL, wv*2, lane);
    layer_mm<8,4,2,256,256>(ws + OFF2H + e*65536, ws + OFF2L + e*65536,
                            b2 + e*256, hH, hL, hH, hL, wv*2, lane);
    layer_mm<8,4,1,256,256>(ws + OFF3H + e*32768, ws + OFF3L + e*32768,
                            b3 + e*128, hH, hL, hH, hL, wv, lane);

    // ---- heads: N=64 (mu|sig), K=128; wave: ntile = wv&3, mtiles (wv>>2)*2+{0,1}
    {
        const unsigned short* WHh = ws + OFFHH + e*8192;
        const unsigned short* WHl = ws + OFFHL + e*8192;
        const int ntl = wv & 3, mt0 = (wv >> 2) << 1;
        const int n = ntl*16 + ln;
        const bool is_mu = (n < 32);
        float bv = is_mu ? bmu[(e<<5)+n] : bsg[(e<<5)+(n-32)];
        f32x4 acc[2] = { (f32x4){bv,bv,bv,bv}, (f32x4){bv,bv,bv,bv} };
        #pragma unroll
        for (int kt = 0; kt < 4; ++kt) {
            const int kcol = kt*32 + lg*8;
            int off = (n << 7) + kcol;
            bf16x8 bh = *reinterpret_cast<const bf16x8*>(&WHh[off]);
            bf16x8 bl = *reinterpret_cast<const bf16x8*>(&WHl[off]);
            #pragma unroll
            for (int m = 0; m < 2; ++m) {
                int row = (mt0 + m)*16 + ln;
                int ae  = row*256 + (kcol ^ (l7 << 3));
                bf16x8 ah = *reinterpret_cast<const bf16x8*>(&hH[ae]);
                bf16x8 al = *reinterpret_cast<const bf16x8*>(&hL[ae]);
                acc[m] = __builtin_amdgcn_mfma_f32_16x16x32_bf16(ah, bh, acc[m], 0, 0, 0);
                acc[m] = __builtin_amdgcn_mfma_f32_16x16x32_bf16(ah, bl, acc[m], 0, 0, 0);
                acc[m] = __builtin_amdgcn_mfma_f32_16x16x32_bf16(al, bh, acc[m], 0, 0, 0);
            }
        }
        float mn_ = 0.0f, mx_ = 0.0f;
        if (!is_mu) { mx_ = mxl[n-32]; mn_ = mnl[n-32]; }
        #pragma unroll
        for (int m = 0; m < 2; ++m) {
            #pragma unroll
            for (int r = 0; r < 4; ++r) {
                int grow = brow0 + (mt0 + m)*16 + lg*4 + r;
                float v = acc[m][r];
                if (is_mu) {
                    v += gs[(size_t)grow*32 + n];
                    out[((size_t)e*BATCH + grow)*32 + n] = v;
                } else {
                    v = soft_clamp_f(v, mn_, mx_);
                    out[(size_t)E_N*BATCH*32 + ((size_t)e*BATCH + grow)*32 + (n-32)] = expf(v);
                }
            }
        }
    }
}

// ============================================================================
// Fallback fp32 kernel (round-0, known-correct) in case ws is too small
// ============================================================================
#define TILE_B  64
#define THREADS 256
#define LDH     260
#define LDX     44
__device__ __forceinline__ float f4c(const float4& v, int i) {
    return reinterpret_cast<const float*>(&v)[i];
}
template<int K, int N, int LDIN, bool SW>
__device__ __forceinline__ void layer_fn(const float* __restrict__ lin,
                                         float* __restrict__ lout,
                                         const float* __restrict__ W,
                                         const float* __restrict__ bias,
                                         int tx, int ty)
{
    constexpr int CH = N / 64;
    float4 acc[4][CH];
    #pragma unroll
    for (int jj = 0; jj < CH; ++jj) {
        float4 bv = *reinterpret_cast<const float4*>(&bias[jj*64 + tx*4]);
        #pragma unroll
        for (int r = 0; r < 4; ++r) acc[r][jj] = bv;
    }
    for (int k0 = 0; k0 < K; k0 += 4) {
        float4 a[4];
        #pragma unroll
        for (int r = 0; r < 4; ++r)
            a[r] = *reinterpret_cast<const float4*>(&lin[(ty*4 + r)*LDIN + k0]);
        #pragma unroll
        for (int kk = 0; kk < 4; ++kk) {
            float4 w[CH];
            #pragma unroll
            for (int jj = 0; jj < CH; ++jj)
                w[jj] = *reinterpret_cast<const float4*>(&W[(k0+kk)*N + jj*64 + tx*4]);
            #pragma unroll
            for (int r = 0; r < 4; ++r) {
                float av = f4c(a[r], kk);
                #pragma unroll
                for (int jj = 0; jj < CH; ++jj) {
                    acc[r][jj].x = fmaf(av, w[jj].x, acc[r][jj].x);
                    acc[r][jj].y = fmaf(av, w[jj].y, acc[r][jj].y);
                    acc[r][jj].z = fmaf(av, w[jj].z, acc[r][jj].z);
                    acc[r][jj].w = fmaf(av, w[jj].w, acc[r][jj].w);
                }
            }
        }
    }
    __syncthreads();
    #pragma unroll
    for (int r = 0; r < 4; ++r) {
        #pragma unroll
        for (int jj = 0; jj < CH; ++jj) {
            float4 v = acc[r][jj];
            if (SW) { v.x = swish_f(v.x); v.y = swish_f(v.y); v.z = swish_f(v.z); v.w = swish_f(v.w); }
            *reinterpret_cast<float4*>(&lout[(ty*4 + r)*LDH + jj*64 + tx*4]) = v;
        }
    }
    __syncthreads();
}
__global__ __launch_bounds__(THREADS, 2)
void ens_fwd(const float* __restrict__ g_state, const float* __restrict__ g_action,
             const float* __restrict__ W0, const float* __restrict__ b0,
             const float* __restrict__ W1, const float* __restrict__ b1,
             const float* __restrict__ W2, const float* __restrict__ b2,
             const float* __restrict__ W3, const float* __restrict__ b3,
             const float* __restrict__ Wmu, const float* __restrict__ bmu,
             const float* __restrict__ Wsg, const float* __restrict__ bsg,
             const float* __restrict__ mxl, const float* __restrict__ mnl,
             float* __restrict__ out)
{
    __shared__ float h[TILE_B * LDH];
    __shared__ float xb[TILE_B * LDX];
    const int tid  = threadIdx.x;
    const int tx   = tid & 15;
    const int ty   = tid >> 4;
    const int e    = blockIdx.x / (BATCH / TILE_B);
    const int brow0 = (blockIdx.x % (BATCH / TILE_B)) * TILE_B;
    for (int i = tid; i < TILE_B * 8; i += THREADS) {
        int r = i >> 3, c = (i & 7) << 2;
        *reinterpret_cast<float4*>(&xb[r*LDX + c]) =
            *reinterpret_cast<const float4*>(&g_state[(size_t)(brow0 + r)*STATE_D + c]);
    }
    if (tid < TILE_B * 2) {
        int r = tid >> 1, c = (tid & 1) << 2;
        *reinterpret_cast<float4*>(&xb[r*LDX + STATE_D + c]) =
            *reinterpret_cast<const float4*>(&g_action[(size_t)(brow0 + r)*ACT_D + c]);
    }
    __syncthreads();
    layer_fn<40,  256, LDX, true>(xb, h, W0 + e*40*256,  b0 + e*256, tx, ty);
    layer_fn<256, 256, LDH, true>(h,  h, W1 + e*256*256, b1 + e*256, tx, ty);
    layer_fn<256, 256, LDH, true>(h,  h, W2 + e*256*256, b2 + e*256, tx, ty);
    layer_fn<256, 128, LDH, true>(h,  h, W3 + e*256*128, b3 + e*128, tx, ty);
    const float* Wm = Wmu + e*128*32;
    const float* Ws = Wsg + e*128*32;
    float2 am[4], as[4];
    {
        float2 bm = *reinterpret_cast<const float2*>(&bmu[e*32 + tx*2]);
        float2 bs = *reinterpret_cast<const float2*>(&bsg[e*32 + tx*2]);
        #pragma unroll
        for (int r = 0; r < 4; ++r) { am[r] = bm; as[r] = bs; }
    }
    for (int k0 = 0; k0 < 128; k0 += 4) {
        float4 a[4];
        #pragma unroll
        for (int r = 0; r < 4; ++r)
            a[r] = *reinterpret_cast<const float4*>(&h[(ty*4 + r)*LDH + k0]);
        #pragma unroll
        for (int kk = 0; kk < 4; ++kk) {
            float2 wm = *reinterpret_cast<const float2*>(&Wm[(k0+kk)*32 + tx*2]);
            float2 ws2 = *reinterpret_cast<const float2*>(&Ws[(k0+kk)*32 + tx*2]);
            #pragma unroll
            for (int r = 0; r < 4; ++r) {
                float av = f4c(a[r], kk);
                am[r].x = fmaf(av, wm.x, am[r].x);
                am[r].y = fmaf(av, wm.y, am[r].y);
                as[r].x = fmaf(av, ws2.x, as[r].x);
                as[r].y = fmaf(av, ws2.y, as[r].y);
            }
        }
    }
    const float2 mx = *reinterpret_cast<const float2*>(&mxl[tx*2]);
    const float2 mn = *reinterpret_cast<const float2*>(&mnl[tx*2]);
    #pragma unroll
    for (int r = 0; r < 4; ++r) {
        const int row = brow0 + ty*4 + r;
        float2 st = *reinterpret_cast<const float2*>(&g_state[(size_t)row*STATE_D + tx*2]);
        float2 mu; mu.x = am[r].x + st.x; mu.y = am[r].y + st.y;
        float2 sg;
        sg.x = expf(soft_clamp_f(as[r].x, mn.x, mx.x));
        sg.y = expf(soft_clamp_f(as[r].y, mn.y, mx.y));
        size_t idx = ((size_t)e*BATCH + row)*DOUT + tx*2;
        *reinterpret_cast<float2*>(&out[idx]) = mu;
        *reinterpret_cast<float2*>(&out[(size_t)E_N*BATCH*DOUT + idx]) = sg;
    }
}

// ============================================================================
extern "C" void kernel_launch(void* const* d_in, const int* in_sizes, int n_in,
                              void* d_out, int out_size, void* d_ws, size_t ws_size,
                              hipStream_t stream) {
    (void)in_sizes; (void)n_in; (void)out_size;
    const float* state  = (const float*)d_in[0];
    const float* action = (const float*)d_in[1];
    const float* W0  = (const float*)d_in[2];
    const float* b0  = (const float*)d_in[3];
    const float* W1  = (const float*)d_in[4];
    const float* b1  = (const float*)d_in[5];
    const float* W2  = (const float*)d_in[6];
    const float* b2  = (const float*)d_in[7];
    const float* W3  = (const float*)d_in[8];
    const float* b3  = (const float*)d_in[9];
    const float* Wmu = (const float*)d_in[10];
    const float* bmu = (const float*)d_in[11];
    const float* Wsg = (const float*)d_in[12];
    const float* bsg = (const float*)d_in[13];
    const float* mxl = (const float*)d_in[14];
    const float* mnl = (const float*)d_in[15];
    float* out = (float*)d_out;

    if (ws_size >= WS_BYTES) {
        unsigned short* ws = (unsigned short*)d_ws;
        prep_w<<<dim3(PREP_N/256), dim3(256), 0, stream>>>(W0, W1, W2, W3, Wmu, Wsg, ws);
        ens_mfma<<<dim3(E_N*512), dim3(512), 0, stream>>>(
            state, action, ws, b0, b1, b2, b3, bmu, bsg, mxl, mnl, out);
    } else {
        ens_fwd<<<dim3(E_N*(BATCH/TILE_B)), dim3(THREADS), 0, stream>>>(
            state, action, W0, b0, W1, b1, W2, b2, W3, b3,
            Wmu, bmu, Wsg, bsg, mxl, mnl, out);
    }
}

// Round 3
// 419.327 us; speedup vs baseline: 3.1604x; 1.3214x over previous
//
#include <hip/hip_runtime.h>
#include <math.h>
#include <stdint.h>

// ---------------- Problem constants ----------------
#define E_N     7
#define BATCH   32768
#define STATE_D 32
#define ACT_D   8
#define DOUT    32

typedef _Float16 f16;
typedef __attribute__((ext_vector_type(8)))  _Float16 f16x8;
typedef __attribute__((ext_vector_type(16))) float    f32x16;

// ---------------- ws layout (f16 elements), fragment-packed ----------------
// slice = one [64 lane][8 elem] fragment-tile group (512 f16 = 1KB)
// order: [L0: 7e x 8nt x 4kt][L1: 7 x 8 x 16][L2: same][L3: 7 x 4 x 16][H: 7 x 2 x 8]
#define OFF_L0  0           // e-stride 16384  (8*4*512)
#define OFF_L1  114688      // e-stride 65536  (8*16*512)
#define OFF_L2  573440
#define OFF_L3  1032192     // e-stride 32768  (4*16*512)
#define OFF_H   1261568     // e-stride 8192   (2*8*512)
#define WS_ELEMS 1318912
#define WS_NEED  ((size_t)WS_ELEMS*2)

// ---------------- common math (identical transcendentals to round 1/2) -----
__device__ __forceinline__ float swish_f(float x) {
    float t = __expf(-x);
    return x * __builtin_amdgcn_rcpf(1.0f + t);
}
__device__ __forceinline__ float softplus_f(float z) {
    return (z > 20.0f) ? z : log1pf(expf(z));
}
__device__ __forceinline__ float soft_clamp_f(float x, float mn, float mx) {
    x = mx - softplus_f(mx - x);
    x = mn + softplus_f(x - mn);
    return x;
}

// ============================================================================
// Prep: pack weights into fp16 fragment order.
// frag for (nt,kt): lane l holds W[k = kt*16 + (l>>5)*8 + j][n = nt*32 + (l&31)]
// Reads are coalesced (lane-consecutive n); writes fully contiguous.
// ============================================================================
#define PREP_THREADS 164864   // 2576 slices * 64 lanes
__global__ __launch_bounds__(256) void prep_f16(
    const float* __restrict__ W0, const float* __restrict__ W1,
    const float* __restrict__ W2, const float* __restrict__ W3,
    const float* __restrict__ Wmu, const float* __restrict__ Wsg,
    unsigned short* __restrict__ ws)
{
    int t = blockIdx.x * 256 + threadIdx.x;
    if (t >= PREP_THREADS) return;
    int slice = t >> 6, l = t & 63;
    int l31 = l & 31, lg = l >> 5;
    const float* src; int e, nt, kt, Ksrc, N; bool head = false;
    if (slice < 224)       { int r = slice;      e=r>>5; r&=31;  nt=r>>2; kt=r&3;  src=W0; Ksrc=40;  N=256; }
    else if (slice < 1120) { int r = slice-224;  e=r>>7; r&=127; nt=r>>4; kt=r&15; src=W1; Ksrc=256; N=256; }
    else if (slice < 2016) { int r = slice-1120; e=r>>7; r&=127; nt=r>>4; kt=r&15; src=W2; Ksrc=256; N=256; }
    else if (slice < 2464) { int r = slice-2016; e=r>>6; r&=63;  nt=r>>4; kt=r&15; src=W3; Ksrc=256; N=128; }
    else                   { int r = slice-2464; e=r>>4; r&=15;  nt=r>>3; kt=r&7;
                             src = (nt==0) ? Wmu : Wsg; Ksrc=128; N=32; head=true; }
    int n  = head ? l31 : nt*32 + l31;
    int k0 = kt*16 + lg*8;
    f16x8 v;
    #pragma unroll
    for (int j = 0; j < 8; ++j) {
        int k = k0 + j;
        float x = (k < Ksrc) ? src[(e*Ksrc + k)*N + n] : 0.0f;
        v[j] = (f16)x;
    }
    *reinterpret_cast<f16x8*>(ws + (size_t)slice*512 + l*8) = v;
}

// ============================================================================
// Fused layer: 64 rows x N cols, fp16 MFMA 32x32x16.
// 4 waves; wave wv owns n-tiles wv*NTW..+NTW-1 (32 cols each), both 32-row tiles.
// A from LDS (XOR-swizzled 16B granules), B from frag-packed global (L1/L2-hot).
// Depth-1 software pipeline on A and B loads. In-place safe (reads, barrier, writes).
// ============================================================================
template<int KT, int NTW, int ASTR, int SWZM>
__device__ __forceinline__ void layer_f16(
    const unsigned short* __restrict__ Wf, const float* __restrict__ bias,
    const unsigned short* __restrict__ aBuf, unsigned short* __restrict__ dBuf,
    int wv, int lane)
{
    const int l31 = lane & 31, lg = lane >> 5;
    const int rowA = l31, rowB = 32 + l31;
    const int abA = rowA * ASTR, abB = rowB * ASTR;
    const int swA = rowA & SWZM, swB = rowB & SWZM;

    f32x16 acc[2][NTW];
    #pragma unroll
    for (int jj = 0; jj < NTW; ++jj) {
        float bv = bias[(wv*NTW + jj)*32 + l31];
        #pragma unroll
        for (int r = 0; r < 16; ++r) { acc[0][jj][r] = bv; acc[1][jj][r] = bv; }
    }
    const unsigned short* wp[NTW];
    #pragma unroll
    for (int jj = 0; jj < NTW; ++jj)
        wp[jj] = Wf + (wv*NTW + jj)*KT*512 + lane*8;

    f16x8 aAc, aBc, bC[NTW], aAn, aBn, bN[NTW];
    {
        int g = lg;  // kt=0
        aAc = *reinterpret_cast<const f16x8*>(aBuf + abA + ((g ^ swA) << 3));
        aBc = *reinterpret_cast<const f16x8*>(aBuf + abB + ((g ^ swB) << 3));
        #pragma unroll
        for (int jj = 0; jj < NTW; ++jj)
            bC[jj] = *reinterpret_cast<const f16x8*>(wp[jj]);
    }
    #pragma unroll
    for (int kt = 0; kt < KT; ++kt) {
        if (kt + 1 < KT) {
            int g = (kt+1)*2 + lg;
            aAn = *reinterpret_cast<const f16x8*>(aBuf + abA + ((g ^ swA) << 3));
            aBn = *reinterpret_cast<const f16x8*>(aBuf + abB + ((g ^ swB) << 3));
            #pragma unroll
            for (int jj = 0; jj < NTW; ++jj)
                bN[jj] = *reinterpret_cast<const f16x8*>(wp[jj] + (kt+1)*512);
        }
        #pragma unroll
        for (int jj = 0; jj < NTW; ++jj) {
            acc[0][jj] = __builtin_amdgcn_mfma_f32_32x32x16_f16(aAc, bC[jj], acc[0][jj], 0, 0, 0);
            acc[1][jj] = __builtin_amdgcn_mfma_f32_32x32x16_f16(aBc, bC[jj], acc[1][jj], 0, 0, 0);
        }
        if (kt + 1 < KT) {
            aAc = aAn; aBc = aBn;
            #pragma unroll
            for (int jj = 0; jj < NTW; ++jj) bC[jj] = bN[jj];
        }
    }
    __syncthreads();   // all reads of aBuf complete -> safe to overwrite
    #pragma unroll
    for (int mt = 0; mt < 2; ++mt) {
        #pragma unroll
        for (int r = 0; r < 16; ++r) {
            int row = mt*32 + (r & 3) + 8*(r >> 2) + 4*lg;
            int rb  = row * 256;
            int swd = row & 15;
            #pragma unroll
            for (int jj = 0; jj < NTW; ++jj) {
                int col = (wv*NTW + jj)*32 + l31;
                float v = swish_f(acc[mt][jj][r]);
                dBuf[rb + (((col >> 3) ^ swd) << 3) + (col & 7)] =
                    __builtin_bit_cast(unsigned short, (f16)v);
            }
        }
    }
    __syncthreads();
}

__global__ __launch_bounds__(256, 4) void ens16(
    const float* __restrict__ gs, const float* __restrict__ ga,
    const unsigned short* __restrict__ ws,
    const float* __restrict__ b0, const float* __restrict__ b1,
    const float* __restrict__ b2, const float* __restrict__ b3,
    const float* __restrict__ bmu, const float* __restrict__ bsg,
    const float* __restrict__ mxl, const float* __restrict__ mnl,
    float* __restrict__ out)
{
    __shared__ unsigned short hbuf[64*256];  // 32 KB
    __shared__ unsigned short xbuf[64*64];   //  8 KB

    const int tid = threadIdx.x, lane = tid & 63, wv = tid >> 6;
    const int e = blockIdx.x >> 9;
    const int brow0 = (blockIdx.x & 511) << 6;

    // ---- stage x = [state | action | zero-pad] as fp16, swizzled ----
    {
        int row = tid >> 2, seg = tid & 3;
        float v[16];
        if (seg < 2) {
            const float4* p = reinterpret_cast<const float4*>(&gs[(size_t)(brow0+row)*32 + seg*16]);
            float4 q0 = p[0], q1 = p[1], q2 = p[2], q3 = p[3];
            v[0]=q0.x; v[1]=q0.y; v[2]=q0.z; v[3]=q0.w;
            v[4]=q1.x; v[5]=q1.y; v[6]=q1.z; v[7]=q1.w;
            v[8]=q2.x; v[9]=q2.y; v[10]=q2.z; v[11]=q2.w;
            v[12]=q3.x; v[13]=q3.y; v[14]=q3.z; v[15]=q3.w;
        } else if (seg == 2) {
            const float4* p = reinterpret_cast<const float4*>(&ga[(size_t)(brow0+row)*8]);
            float4 q0 = p[0], q1 = p[1];
            v[0]=q0.x; v[1]=q0.y; v[2]=q0.z; v[3]=q0.w;
            v[4]=q1.x; v[5]=q1.y; v[6]=q1.z; v[7]=q1.w;
            #pragma unroll
            for (int i = 8; i < 16; ++i) v[i] = 0.0f;
        } else {
            #pragma unroll
            for (int i = 0; i < 16; ++i) v[i] = 0.0f;
        }
        f16x8 h0, h1;
        #pragma unroll
        for (int i = 0; i < 8; ++i) { h0[i] = (f16)v[i]; h1[i] = (f16)v[8+i]; }
        int sw = row & 7, g0 = seg*2;
        *reinterpret_cast<f16x8*>(xbuf + row*64 + (((g0  ) ^ sw) << 3)) = h0;
        *reinterpret_cast<f16x8*>(xbuf + row*64 + (((g0+1) ^ sw) << 3)) = h1;
    }
    __syncthreads();

    // ---- layer chain ----
    layer_f16<4, 2, 64, 7 >(ws + OFF_L0 + e*16384, b0 + e*256, xbuf, hbuf, wv, lane);
    layer_f16<16,2, 256,15>(ws + OFF_L1 + e*65536, b1 + e*256, hbuf, hbuf, wv, lane);
    layer_f16<16,2, 256,15>(ws + OFF_L2 + e*65536, b2 + e*256, hbuf, hbuf, wv, lane);
    layer_f16<16,1, 256,15>(ws + OFF_L3 + e*32768, b3 + e*128, hbuf, hbuf, wv, lane);

    // ---- heads: N=64 (mu|sig), K=128; wave wv: mt=wv>>1, nt=wv&1 ----
    {
        const unsigned short* WH = ws + OFF_H + e*8192;
        const int mt = wv >> 1, ntH = wv & 1;
        const int l31 = lane & 31, lg = lane >> 5;
        float bvH = (ntH == 0) ? bmu[e*32 + l31] : bsg[e*32 + l31];
        f32x16 acc;
        #pragma unroll
        for (int r = 0; r < 16; ++r) acc[r] = bvH;
        const unsigned short* wpH = WH + ntH*8*512 + lane*8;
        const int row0 = mt*32 + l31, ab = row0*256, sw = row0 & 15;
        f16x8 ac, bc, an, bn;
        ac = *reinterpret_cast<const f16x8*>(hbuf + ab + ((lg ^ sw) << 3));
        bc = *reinterpret_cast<const f16x8*>(wpH);
        #pragma unroll
        for (int kt = 0; kt < 8; ++kt) {
            if (kt < 7) {
                int g = (kt+1)*2 + lg;
                an = *reinterpret_cast<const f16x8*>(hbuf + ab + ((g ^ sw) << 3));
                bn = *reinterpret_cast<const f16x8*>(wpH + (kt+1)*512);
            }
            acc = __builtin_amdgcn_mfma_f32_32x32x16_f16(ac, bc, acc, 0, 0, 0);
            if (kt < 7) { ac = an; bc = bn; }
        }
        if (ntH == 0) {
            #pragma unroll
            for (int r = 0; r < 16; ++r) {
                int grow = brow0 + mt*32 + (r & 3) + 8*(r >> 2) + 4*lg;
                float v = acc[r] + gs[(size_t)grow*32 + l31];
                out[((size_t)e*BATCH + grow)*32 + l31] = v;
            }
        } else {
            float mx = mxl[l31], mn = mnl[l31];
            #pragma unroll
            for (int r = 0; r < 16; ++r) {
                int grow = brow0 + mt*32 + (r & 3) + 8*(r >> 2) + 4*lg;
                float v = expf(soft_clamp_f(acc[r], mn, mx));
                out[(size_t)E_N*BATCH*32 + ((size_t)e*BATCH + grow)*32 + l31] = v;
            }
        }
    }
}

// ============================================================================
// Fallback fp32 kernel (round-0, known-correct) in case ws is too small
// ============================================================================
#define TILE_B  64
#define THREADS 256
#define LDH     260
#define LDX     44
__device__ __forceinline__ float f4c(const float4& v, int i) {
    return reinterpret_cast<const float*>(&v)[i];
}
template<int K, int N, int LDIN, bool SW>
__device__ __forceinline__ void layer_fn(const float* __restrict__ lin,
                                         float* __restrict__ lout,
                                         const float* __restrict__ W,
                                         const float* __restrict__ bias,
                                         int tx, int ty)
{
    constexpr int CH = N / 64;
    float4 acc[4][CH];
    #pragma unroll
    for (int jj = 0; jj < CH; ++jj) {
        float4 bv = *reinterpret_cast<const float4*>(&bias[jj*64 + tx*4]);
        #pragma unroll
        for (int r = 0; r < 4; ++r) acc[r][jj] = bv;
    }
    for (int k0 = 0; k0 < K; k0 += 4) {
        float4 a[4];
        #pragma unroll
        for (int r = 0; r < 4; ++r)
            a[r] = *reinterpret_cast<const float4*>(&lin[(ty*4 + r)*LDIN + k0]);
        #pragma unroll
        for (int kk = 0; kk < 4; ++kk) {
            float4 w[CH];
            #pragma unroll
            for (int jj = 0; jj < CH; ++jj)
                w[jj] = *reinterpret_cast<const float4*>(&W[(k0+kk)*N + jj*64 + tx*4]);
            #pragma unroll
            for (int r = 0; r < 4; ++r) {
                float av = f4c(a[r], kk);
                #pragma unroll
                for (int jj = 0; jj < CH; ++jj) {
                    acc[r][jj].x = fmaf(av, w[jj].x, acc[r][jj].x);
                    acc[r][jj].y = fmaf(av, w[jj].y, acc[r][jj].y);
                    acc[r][jj].z = fmaf(av, w[jj].z, acc[r][jj].z);
                    acc[r][jj].w = fmaf(av, w[jj].w, acc[r][jj].w);
                }
            }
        }
    }
    __syncthreads();
    #pragma unroll
    for (int r = 0; r < 4; ++r) {
        #pragma unroll
        for (int jj = 0; jj < CH; ++jj) {
            float4 v = acc[r][jj];
            if (SW) { v.x = swish_f(v.x); v.y = swish_f(v.y); v.z = swish_f(v.z); v.w = swish_f(v.w); }
            *reinterpret_cast<float4*>(&lout[(ty*4 + r)*LDH + jj*64 + tx*4]) = v;
        }
    }
    __syncthreads();
}
__global__ __launch_bounds__(THREADS, 2)
void ens_fwd(const float* __restrict__ g_state, const float* __restrict__ g_action,
             const float* __restrict__ W0, const float* __restrict__ b0,
             const float* __restrict__ W1, const float* __restrict__ b1,
             const float* __restrict__ W2, const float* __restrict__ b2,
             const float* __restrict__ W3, const float* __restrict__ b3,
             const float* __restrict__ Wmu, const float* __restrict__ bmu,
             const float* __restrict__ Wsg, const float* __restrict__ bsg,
             const float* __restrict__ mxl, const float* __restrict__ mnl,
             float* __restrict__ out)
{
    __shared__ float h[TILE_B * LDH];
    __shared__ float xb[TILE_B * LDX];
    const int tid  = threadIdx.x;
    const int tx   = tid & 15;
    const int ty   = tid >> 4;
    const int e    = blockIdx.x / (BATCH / TILE_B);
    const int brow0 = (blockIdx.x % (BATCH / TILE_B)) * TILE_B;
    for (int i = tid; i < TILE_B * 8; i += THREADS) {
        int r = i >> 3, c = (i & 7) << 2;
        *reinterpret_cast<float4*>(&xb[r*LDX + c]) =
            *reinterpret_cast<const float4*>(&g_state[(size_t)(brow0 + r)*STATE_D + c]);
    }
    if (tid < TILE_B * 2) {
        int r = tid >> 1, c = (tid & 1) << 2;
        *reinterpret_cast<float4*>(&xb[r*LDX + STATE_D + c]) =
            *reinterpret_cast<const float4*>(&g_action[(size_t)(brow0 + r)*ACT_D + c]);
    }
    __syncthreads();
    layer_fn<40,  256, LDX, true>(xb, h, W0 + e*40*256,  b0 + e*256, tx, ty);
    layer_fn<256, 256, LDH, true>(h,  h, W1 + e*256*256, b1 + e*256, tx, ty);
    layer_fn<256, 256, LDH, true>(h,  h, W2 + e*256*256, b2 + e*256, tx, ty);
    layer_fn<256, 128, LDH, true>(h,  h, W3 + e*256*128, b3 + e*128, tx, ty);
    const float* Wm = Wmu + e*128*32;
    const float* Ws = Wsg + e*128*32;
    float2 am[4], as[4];
    {
        float2 bm = *reinterpret_cast<const float2*>(&bmu[e*32 + tx*2]);
        float2 bs = *reinterpret_cast<const float2*>(&bsg[e*32 + tx*2]);
        #pragma unroll
        for (int r = 0; r < 4; ++r) { am[r] = bm; as[r] = bs; }
    }
    for (int k0 = 0; k0 < 128; k0 += 4) {
        float4 a[4];
        #pragma unroll
        for (int r = 0; r < 4; ++r)
            a[r] = *reinterpret_cast<const float4*>(&h[(ty*4 + r)*LDH + k0]);
        #pragma unroll
        for (int kk = 0; kk < 4; ++kk) {
            float2 wm = *reinterpret_cast<const float2*>(&Wm[(k0+kk)*32 + tx*2]);
            float2 ws2 = *reinterpret_cast<const float2*>(&Ws[(k0+kk)*32 + tx*2]);
            #pragma unroll
            for (int r = 0; r < 4; ++r) {
                float av = f4c(a[r], kk);
                am[r].x = fmaf(av, wm.x, am[r].x);
                am[r].y = fmaf(av, wm.y, am[r].y);
                as[r].x = fmaf(av, ws2.x, as[r].x);
                as[r].y = fmaf(av, ws2.y, as[r].y);
            }
        }
    }
    const float2 mx = *reinterpret_cast<const float2*>(&mxl[tx*2]);
    const float2 mn = *reinterpret_cast<const float2*>(&mnl[tx*2]);
    #pragma unroll
    for (int r = 0; r < 4; ++r) {
        const int row = brow0 + ty*4 + r;
        float2 st = *reinterpret_cast<const float2*>(&g_state[(size_t)row*STATE_D + tx*2]);
        float2 mu; mu.x = am[r].x + st.x; mu.y = am[r].y + st.y;
        float2 sg;
        sg.x = expf(soft_clamp_f(as[r].x, mn.x, mx.x));
        sg.y = expf(soft_clamp_f(as[r].y, mn.y, mx.y));
        size_t idx = ((size_t)e*BATCH + row)*DOUT + tx*2;
        *reinterpret_cast<float2*>(&out[idx]) = mu;
        *reinterpret_cast<float2*>(&out[(size_t)E_N*BATCH*DOUT + idx]) = sg;
    }
}

// ============================================================================
extern "C" void kernel_launch(void* const* d_in, const int* in_sizes, int n_in,
                              void* d_out, int out_size, void* d_ws, size_t ws_size,
                              hipStream_t stream) {
    (void)in_sizes; (void)n_in; (void)out_size;
    const float* state  = (const float*)d_in[0];
    const float* action = (const float*)d_in[1];
    const float* W0  = (const float*)d_in[2];
    const float* b0  = (const float*)d_in[3];
    const float* W1  = (const float*)d_in[4];
    const float* b1  = (const float*)d_in[5];
    const float* W2  = (const float*)d_in[6];
    const float* b2  = (const float*)d_in[7];
    const float* W3  = (const float*)d_in[8];
    const float* b3  = (const float*)d_in[9];
    const float* Wmu = (const float*)d_in[10];
    const float* bmu = (const float*)d_in[11];
    const float* Wsg = (const float*)d_in[12];
    const float* bsg = (const float*)d_in[13];
    const float* mxl = (const float*)d_in[14];
    const float* mnl = (const float*)d_in[15];
    float* out = (float*)d_out;

    if (ws_size >= WS_NEED) {
        unsigned short* ws = (unsigned short*)d_ws;
        prep_f16<<<dim3((PREP_THREADS + 255)/256), dim3(256), 0, stream>>>(
            W0, W1, W2, W3, Wmu, Wsg, ws);
        ens16<<<dim3(E_N * 512), dim3(256), 0, stream>>>(
            state, action, ws, b0, b1, b2, b3, bmu, bsg, mxl, mnl, out);
    } else {
        ens_fwd<<<dim3(E_N * (BATCH/TILE_B)), dim3(THREADS), 0, stream>>>(
            state, action, W0, b0, W1, b1, W2, b2, W3, b3,
            Wmu, bmu, Wsg, bsg, mxl, mnl, out);
    }
}

// Round 4
// 301.277 us; speedup vs baseline: 4.3987x; 1.3918x over previous
//
#include <hip/hip_runtime.h>
#include <math.h>
#include <stdint.h>

// ---------------- Problem constants ----------------
#define E_N     7
#define BATCH   32768
#define STATE_D 32
#define ACT_D   8
#define DOUT    32

typedef _Float16 f16;
typedef __attribute__((ext_vector_type(4)))  _Float16 f16x4;
typedef __attribute__((ext_vector_type(8)))  _Float16 f16x8;
typedef __attribute__((ext_vector_type(16))) float    f32x16;

// ---------------- ws layout (f16 elements), fragment-packed ----------------
// slice = one [64 lane][8 elem] fragment-tile group (512 f16 = 1KB)
// frag (nt,kt): lane l holds W[k = kt*16 + (l>>5)*8 + j][n = nt*32 + (l&31)]
// This layout serves as MFMA A-frag (row=n) or B-frag (col=n) identically.
#define OFF_L0  0           // e-stride 16384  (8nt*4kt*512)
#define OFF_L1  114688      // e-stride 65536  (8*16*512)
#define OFF_L2  573440
#define OFF_L3  1032192     // e-stride 32768  (4*16*512)
#define OFF_H   1261568     // e-stride 8192   (2*8*512)
#define WS_ELEMS 1318912
#define WS_NEED  ((size_t)WS_ELEMS*2)

// ---------------- common math ----------------
__device__ __forceinline__ float swish_f(float x) {
    float t = __expf(-x);
    return x * __builtin_amdgcn_rcpf(1.0f + t);
}
__device__ __forceinline__ float softplus_f(float z) {
    return (z > 20.0f) ? z : log1pf(expf(z));
}
__device__ __forceinline__ float soft_clamp_f(float x, float mn, float mx) {
    x = mx - softplus_f(mx - x);
    x = mn + softplus_f(x - mn);
    return x;
}

// ============================================================================
// Prep: pack weights into fp16 fragment order (unchanged from round 3).
// ============================================================================
#define PREP_THREADS 164864   // 2576 slices * 64 lanes
__global__ __launch_bounds__(256) void prep_f16(
    const float* __restrict__ W0, const float* __restrict__ W1,
    const float* __restrict__ W2, const float* __restrict__ W3,
    const float* __restrict__ Wmu, const float* __restrict__ Wsg,
    unsigned short* __restrict__ ws)
{
    int t = blockIdx.x * 256 + threadIdx.x;
    if (t >= PREP_THREADS) return;
    int slice = t >> 6, l = t & 63;
    int l31 = l & 31, lg = l >> 5;
    const float* src; int e, nt, kt, Ksrc, N; bool head = false;
    if (slice < 224)       { int r = slice;      e=r>>5; r&=31;  nt=r>>2; kt=r&3;  src=W0; Ksrc=40;  N=256; }
    else if (slice < 1120) { int r = slice-224;  e=r>>7; r&=127; nt=r>>4; kt=r&15; src=W1; Ksrc=256; N=256; }
    else if (slice < 2016) { int r = slice-1120; e=r>>7; r&=127; nt=r>>4; kt=r&15; src=W2; Ksrc=256; N=256; }
    else if (slice < 2464) { int r = slice-2016; e=r>>6; r&=63;  nt=r>>4; kt=r&15; src=W3; Ksrc=256; N=128; }
    else                   { int r = slice-2464; e=r>>4; r&=15;  nt=r>>3; kt=r&7;
                             src = (nt==0) ? Wmu : Wsg; Ksrc=128; N=32; head=true; }
    int n  = head ? l31 : nt*32 + l31;
    int k0 = kt*16 + lg*8;
    f16x8 v;
    #pragma unroll
    for (int j = 0; j < 8; ++j) {
        int k = k0 + j;
        float x = (k < Ksrc) ? src[(e*Ksrc + k)*N + n] : 0.0f;
        v[j] = (f16)x;
    }
    *reinterpret_cast<f16x8*>(ws + (size_t)slice*512 + l*8) = v;
}

// ============================================================================
// Hidden layer, SWAPPED operands: acc = mfma(W_frag, act_frag).
// Output: lane holds batch row m = mt*32 + (lane&31); 16 regs = feature cols
// n = nt*32 + (r&3) + 8*(r>>2) + 4*lg  -> 4 groups of 4 CONTIGUOUS cols.
// Epilogue: bias(+float4) + swish + pack f16x4 -> ds_write_b64 (16 per wave).
// No software pipeline (register pressure; compiler schedules lgkmcnt fine).
// ============================================================================
template<int KT, int NTW, int ASTR, int SWZM>
__device__ __forceinline__ void layer_sw(
    const unsigned short* __restrict__ Wf, const float* __restrict__ bias,
    const unsigned short* __restrict__ aBuf, unsigned short* __restrict__ dBuf,
    int nt0, int lane)
{
    const int l31 = lane & 31, lg = lane >> 5;
    f32x16 acc[2][NTW];
    #pragma unroll
    for (int mt = 0; mt < 2; ++mt)
        #pragma unroll
        for (int jj = 0; jj < NTW; ++jj)
            #pragma unroll
            for (int r = 0; r < 16; ++r) acc[mt][jj][r] = 0.0f;

    const int ab0 = l31*ASTR, ab1 = (32 + l31)*ASTR;
    const int sw0 = l31 & SWZM, sw1 = (32 + l31) & SWZM;

    #pragma unroll
    for (int kt = 0; kt < KT; ++kt) {
        const int kg = kt*2 + lg;
        f16x8 w[NTW];
        #pragma unroll
        for (int jj = 0; jj < NTW; ++jj)
            w[jj] = *reinterpret_cast<const f16x8*>(Wf + (nt0+jj)*KT*512 + kt*512 + lane*8);
        f16x8 a0 = *reinterpret_cast<const f16x8*>(aBuf + ab0 + ((kg ^ sw0) << 3));
        f16x8 a1 = *reinterpret_cast<const f16x8*>(aBuf + ab1 + ((kg ^ sw1) << 3));
        #pragma unroll
        for (int jj = 0; jj < NTW; ++jj) {
            acc[0][jj] = __builtin_amdgcn_mfma_f32_32x32x16_f16(w[jj], a0, acc[0][jj], 0, 0, 0);
            acc[1][jj] = __builtin_amdgcn_mfma_f32_32x32x16_f16(w[jj], a1, acc[1][jj], 0, 0, 0);
        }
    }
    __syncthreads();   // all reads of aBuf complete -> safe to overwrite in place
    #pragma unroll
    for (int mt = 0; mt < 2; ++mt) {
        const int m  = mt*32 + l31;
        const int rb = m*256, swd = m & 15;
        #pragma unroll
        for (int jj = 0; jj < NTW; ++jj) {
            const int nb = (nt0+jj)*32 + 4*lg;
            #pragma unroll
            for (int g = 0; g < 4; ++g) {
                float4 bv = *reinterpret_cast<const float4*>(&bias[nb + 8*g]);
                f16x4 pk;
                pk[0] = (f16)swish_f(acc[mt][jj][4*g+0] + bv.x);
                pk[1] = (f16)swish_f(acc[mt][jj][4*g+1] + bv.y);
                pk[2] = (f16)swish_f(acc[mt][jj][4*g+2] + bv.z);
                pk[3] = (f16)swish_f(acc[mt][jj][4*g+3] + bv.w);
                const int cg = (nt0+jj)*4 + g;
                *reinterpret_cast<f16x4*>(dBuf + rb + ((cg ^ swd) << 3) + 4*lg) = pk;
            }
        }
    }
    __syncthreads();
}

__global__ __launch_bounds__(256, 4) void ens16(
    const float* __restrict__ gs, const float* __restrict__ ga,
    const unsigned short* __restrict__ ws,
    const float* __restrict__ b0, const float* __restrict__ b1,
    const float* __restrict__ b2, const float* __restrict__ b3,
    const float* __restrict__ bmu, const float* __restrict__ bsg,
    const float* __restrict__ mxl, const float* __restrict__ mnl,
    float* __restrict__ out)
{
    __shared__ unsigned short hbuf[64*256];  // 32 KB
    __shared__ unsigned short xbuf[64*64];   //  8 KB

    const int tid = threadIdx.x, lane = tid & 63, wv = tid >> 6;
    const int e = blockIdx.x >> 9;
    const int brow0 = (blockIdx.x & 511) << 6;

    // ---- stage x = [state | action | zero-pad] as fp16, swizzled ----
    {
        int row = tid >> 2, seg = tid & 3;
        float v[16];
        if (seg < 2) {
            const float4* p = reinterpret_cast<const float4*>(&gs[(size_t)(brow0+row)*32 + seg*16]);
            float4 q0 = p[0], q1 = p[1], q2 = p[2], q3 = p[3];
            v[0]=q0.x; v[1]=q0.y; v[2]=q0.z; v[3]=q0.w;
            v[4]=q1.x; v[5]=q1.y; v[6]=q1.z; v[7]=q1.w;
            v[8]=q2.x; v[9]=q2.y; v[10]=q2.z; v[11]=q2.w;
            v[12]=q3.x; v[13]=q3.y; v[14]=q3.z; v[15]=q3.w;
        } else if (seg == 2) {
            const float4* p = reinterpret_cast<const float4*>(&ga[(size_t)(brow0+row)*8]);
            float4 q0 = p[0], q1 = p[1];
            v[0]=q0.x; v[1]=q0.y; v[2]=q0.z; v[3]=q0.w;
            v[4]=q1.x; v[5]=q1.y; v[6]=q1.z; v[7]=q1.w;
            #pragma unroll
            for (int i = 8; i < 16; ++i) v[i] = 0.0f;
        } else {
            #pragma unroll
            for (int i = 0; i < 16; ++i) v[i] = 0.0f;
        }
        f16x8 h0, h1;
        #pragma unroll
        for (int i = 0; i < 8; ++i) { h0[i] = (f16)v[i]; h1[i] = (f16)v[8+i]; }
        int sw = row & 7, g0 = seg*2;
        *reinterpret_cast<f16x8*>(xbuf + row*64 + (((g0  ) ^ sw) << 3)) = h0;
        *reinterpret_cast<f16x8*>(xbuf + row*64 + (((g0+1) ^ sw) << 3)) = h1;
    }
    __syncthreads();

    // ---- hidden chain (swapped operands) ----
    layer_sw<4, 2, 64, 7 >(ws + OFF_L0 + e*16384, b0 + e*256, xbuf, hbuf, wv*2, lane);
    layer_sw<16,2, 256,15>(ws + OFF_L1 + e*65536, b1 + e*256, hbuf, hbuf, wv*2, lane);
    layer_sw<16,2, 256,15>(ws + OFF_L2 + e*65536, b2 + e*256, hbuf, hbuf, wv*2, lane);
    layer_sw<16,1, 256,15>(ws + OFF_L3 + e*32768, b3 + e*128, hbuf, hbuf, wv,   lane);

    // ---- heads (normal orientation): N=64 (mu|sig), K=128 ----
    {
        const unsigned short* WH = ws + OFF_H + e*8192;
        const int mt = wv >> 1, ntH = wv & 1;
        const int l31 = lane & 31, lg = lane >> 5;
        float bvH = (ntH == 0) ? bmu[e*32 + l31] : bsg[e*32 + l31];
        f32x16 acc;
        #pragma unroll
        for (int r = 0; r < 16; ++r) acc[r] = bvH;
        const unsigned short* wpH = WH + ntH*8*512 + lane*8;
        const int row0 = mt*32 + l31, ab = row0*256, sw = row0 & 15;
        #pragma unroll
        for (int kt = 0; kt < 8; ++kt) {
            int kg = kt*2 + lg;
            f16x8 ac = *reinterpret_cast<const f16x8*>(hbuf + ab + ((kg ^ sw) << 3));
            f16x8 bc = *reinterpret_cast<const f16x8*>(wpH + kt*512);
            acc = __builtin_amdgcn_mfma_f32_32x32x16_f16(ac, bc, acc, 0, 0, 0);
        }
        if (ntH == 0) {
            #pragma unroll
            for (int r = 0; r < 16; ++r) {
                int grow = brow0 + mt*32 + (r & 3) + 8*(r >> 2) + 4*lg;
                float v = acc[r] + gs[(size_t)grow*32 + l31];
                __builtin_nontemporal_store(v, &out[((size_t)e*BATCH + grow)*32 + l31]);
            }
        } else {
            float mx = mxl[l31], mn = mnl[l31];
            #pragma unroll
            for (int r = 0; r < 16; ++r) {
                int grow = brow0 + mt*32 + (r & 3) + 8*(r >> 2) + 4*lg;
                float v = expf(soft_clamp_f(acc[r], mn, mx));
                __builtin_nontemporal_store(v,
                    &out[(size_t)E_N*BATCH*32 + ((size_t)e*BATCH + grow)*32 + l31]);
            }
        }
    }
}

// ============================================================================
// Fallback fp32 kernel (round-0, known-correct) in case ws is too small
// ============================================================================
#define TILE_B  64
#define THREADS 256
#define LDH     260
#define LDX     44
__device__ __forceinline__ float f4c(const float4& v, int i) {
    return reinterpret_cast<const float*>(&v)[i];
}
template<int K, int N, int LDIN, bool SW>
__device__ __forceinline__ void layer_fn(const float* __restrict__ lin,
                                         float* __restrict__ lout,
                                         const float* __restrict__ W,
                                         const float* __restrict__ bias,
                                         int tx, int ty)
{
    constexpr int CH = N / 64;
    float4 acc[4][CH];
    #pragma unroll
    for (int jj = 0; jj < CH; ++jj) {
        float4 bv = *reinterpret_cast<const float4*>(&bias[jj*64 + tx*4]);
        #pragma unroll
        for (int r = 0; r < 4; ++r) acc[r][jj] = bv;
    }
    for (int k0 = 0; k0 < K; k0 += 4) {
        float4 a[4];
        #pragma unroll
        for (int r = 0; r < 4; ++r)
            a[r] = *reinterpret_cast<const float4*>(&lin[(ty*4 + r)*LDIN + k0]);
        #pragma unroll
        for (int kk = 0; kk < 4; ++kk) {
            float4 w[CH];
            #pragma unroll
            for (int jj = 0; jj < CH; ++jj)
                w[jj] = *reinterpret_cast<const float4*>(&W[(k0+kk)*N + jj*64 + tx*4]);
            #pragma unroll
            for (int r = 0; r < 4; ++r) {
                float av = f4c(a[r], kk);
                #pragma unroll
                for (int jj = 0; jj < CH; ++jj) {
                    acc[r][jj].x = fmaf(av, w[jj].x, acc[r][jj].x);
                    acc[r][jj].y = fmaf(av, w[jj].y, acc[r][jj].y);
                    acc[r][jj].z = fmaf(av, w[jj].z, acc[r][jj].z);
                    acc[r][jj].w = fmaf(av, w[jj].w, acc[r][jj].w);
                }
            }
        }
    }
    __syncthreads();
    #pragma unroll
    for (int r = 0; r < 4; ++r) {
        #pragma unroll
        for (int jj = 0; jj < CH; ++jj) {
            float4 v = acc[r][jj];
            if (SW) { v.x = swish_f(v.x); v.y = swish_f(v.y); v.z = swish_f(v.z); v.w = swish_f(v.w); }
            *reinterpret_cast<float4*>(&lout[(ty*4 + r)*LDH + jj*64 + tx*4]) = v;
        }
    }
    __syncthreads();
}
__global__ __launch_bounds__(THREADS, 2)
void ens_fwd(const float* __restrict__ g_state, const float* __restrict__ g_action,
             const float* __restrict__ W0, const float* __restrict__ b0,
             const float* __restrict__ W1, const float* __restrict__ b1,
             const float* __restrict__ W2, const float* __restrict__ b2,
             const float* __restrict__ W3, const float* __restrict__ b3,
             const float* __restrict__ Wmu, const float* __restrict__ bmu,
             const float* __restrict__ Wsg, const float* __restrict__ bsg,
             const float* __restrict__ mxl, const float* __restrict__ mnl,
             float* __restrict__ out)
{
    __shared__ float h[TILE_B * LDH];
    __shared__ float xb[TILE_B * LDX];
    const int tid  = threadIdx.x;
    const int tx   = tid & 15;
    const int ty   = tid >> 4;
    const int e    = blockIdx.x / (BATCH / TILE_B);
    const int brow0 = (blockIdx.x % (BATCH / TILE_B)) * TILE_B;
    for (int i = tid; i < TILE_B * 8; i += THREADS) {
        int r = i >> 3, c = (i & 7) << 2;
        *reinterpret_cast<float4*>(&xb[r*LDX + c]) =
            *reinterpret_cast<const float4*>(&g_state[(size_t)(brow0 + r)*STATE_D + c]);
    }
    if (tid < TILE_B * 2) {
        int r = tid >> 1, c = (tid & 1) << 2;
        *reinterpret_cast<float4*>(&xb[r*LDX + STATE_D + c]) =
            *reinterpret_cast<const float4*>(&g_action[(size_t)(brow0 + r)*ACT_D + c]);
    }
    __syncthreads();
    layer_fn<40,  256, LDX, true>(xb, h, W0 + e*40*256,  b0 + e*256, tx, ty);
    layer_fn<256, 256, LDH, true>(h,  h, W1 + e*256*256, b1 + e*256, tx, ty);
    layer_fn<256, 256, LDH, true>(h,  h, W2 + e*256*256, b2 + e*256, tx, ty);
    layer_fn<256, 128, LDH, true>(h,  h, W3 + e*256*128, b3 + e*128, tx, ty);
    const float* Wm = Wmu + e*128*32;
    const float* Ws = Wsg + e*128*32;
    float2 am[4], as[4];
    {
        float2 bm = *reinterpret_cast<const float2*>(&bmu[e*32 + tx*2]);
        float2 bs = *reinterpret_cast<const float2*>(&bsg[e*32 + tx*2]);
        #pragma unroll
        for (int r = 0; r < 4; ++r) { am[r] = bm; as[r] = bs; }
    }
    for (int k0 = 0; k0 < 128; k0 += 4) {
        float4 a[4];
        #pragma unroll
        for (int r = 0; r < 4; ++r)
            a[r] = *reinterpret_cast<const float4*>(&h[(ty*4 + r)*LDH + k0]);
        #pragma unroll
        for (int kk = 0; kk < 4; ++kk) {
            float2 wm = *reinterpret_cast<const float2*>(&Wm[(k0+kk)*32 + tx*2]);
            float2 ws2 = *reinterpret_cast<const float2*>(&Ws[(k0+kk)*32 + tx*2]);
            #pragma unroll
            for (int r = 0; r < 4; ++r) {
                float av = f4c(a[r], kk);
                am[r].x = fmaf(av, wm.x, am[r].x);
                am[r].y = fmaf(av, wm.y, am[r].y);
                as[r].x = fmaf(av, ws2.x, as[r].x);
                as[r].y = fmaf(av, ws2.y, as[r].y);
            }
        }
    }
    const float2 mx = *reinterpret_cast<const float2*>(&mxl[tx*2]);
    const float2 mn = *reinterpret_cast<const float2*>(&mnl[tx*2]);
    #pragma unroll
    for (int r = 0; r < 4; ++r) {
        const int row = brow0 + ty*4 + r;
        float2 st = *reinterpret_cast<const float2*>(&g_state[(size_t)row*STATE_D + tx*2]);
        float2 mu; mu.x = am[r].x + st.x; mu.y = am[r].y + st.y;
        float2 sg;
        sg.x = expf(soft_clamp_f(as[r].x, mn.x, mx.x));
        sg.y = expf(soft_clamp_f(as[r].y, mn.y, mx.y));
        size_t idx = ((size_t)e*BATCH + row)*DOUT + tx*2;
        *reinterpret_cast<float2*>(&out[idx]) = mu;
        *reinterpret_cast<float2*>(&out[(size_t)E_N*BATCH*DOUT + idx]) = sg;
    }
}

// ============================================================================
extern "C" void kernel_launch(void* const* d_in, const int* in_sizes, int n_in,
                              void* d_out, int out_size, void* d_ws, size_t ws_size,
                              hipStream_t stream) {
    (void)in_sizes; (void)n_in; (void)out_size;
    const float* state  = (const float*)d_in[0];
    const float* action = (const float*)d_in[1];
    const float* W0  = (const float*)d_in[2];
    const float* b0  = (const float*)d_in[3];
    const float* W1  = (const float*)d_in[4];
    const float* b1  = (const float*)d_in[5];
    const float* W2  = (const float*)d_in[6];
    const float* b2  = (const float*)d_in[7];
    const float* W3  = (const float*)d_in[8];
    const float* b3  = (const float*)d_in[9];
    const float* Wmu = (const float*)d_in[10];
    const float* bmu = (const float*)d_in[11];
    const float* Wsg = (const float*)d_in[12];
    const float* bsg = (const float*)d_in[13];
    const float* mxl = (const float*)d_in[14];
    const float* mnl = (const float*)d_in[15];
    float* out = (float*)d_out;

    if (ws_size >= WS_NEED) {
        unsigned short* ws = (unsigned short*)d_ws;
        prep_f16<<<dim3((PREP_THREADS + 255)/256), dim3(256), 0, stream>>>(
            W0, W1, W2, W3, Wmu, Wsg, ws);
        ens16<<<dim3(E_N * 512), dim3(256), 0, stream>>>(
            state, action, ws, b0, b1, b2, b3, bmu, bsg, mxl, mnl, out);
    } else {
        ens_fwd<<<dim3(E_N * (BATCH/TILE_B)), dim3(THREADS), 0, stream>>>(
            state, action, W0, b0, W1, b1, W2, b2, W3, b3,
            Wmu, bmu, Wsg, bsg, mxl, mnl, out);
    }
}

// Round 5
// 248.353 us; speedup vs baseline: 5.3361x; 1.2131x over previous
//
#include <hip/hip_runtime.h>
#include <math.h>
#include <stdint.h>

// ---------------- Problem constants ----------------
#define E_N     7
#define BATCH   32768
#define STATE_D 32
#define ACT_D   8
#define DOUT    32

typedef _Float16 f16;
typedef __attribute__((ext_vector_type(4)))  _Float16 f16x4;
typedef __attribute__((ext_vector_type(8)))  _Float16 f16x8;
typedef __attribute__((ext_vector_type(16))) float    f32x16;

// ---------------- ws layout (f16 elements), fragment-packed ----------------
// slice = one [64 lane][8 elem] fragment-tile group (512 f16 = 1KB)
// frag (nt,kt): lane l holds W[k = kt*16 + (l>>5)*8 + j][n = nt*32 + (l&31)]
// Serves as MFMA A-frag (row=n) or B-frag (col=n) identically.
#define OFF_L0  0           // e-stride 16384  (8nt*4kt*512)
#define OFF_L1  114688      // e-stride 65536  (8*16*512)
#define OFF_L2  573440
#define OFF_L3  1032192     // e-stride 32768  (4*16*512)
#define OFF_H   1261568     // e-stride 8192   (2*8*512)
#define WS_ELEMS 1318912
#define WS_NEED  ((size_t)WS_ELEMS*2)

// ---------------- fast math (hardware trans ops only, no libm) ----------------
__device__ __forceinline__ float swish_f(float x) {
    float t = __expf(-x);
    return x * __builtin_amdgcn_rcpf(1.0f + t);
}
__device__ __forceinline__ float softplus_fast(float z) {
    float sp = __logf(1.0f + __expf(z));   // z>88: inf -> select takes z
    return (z > 20.0f) ? z : sp;
}
__device__ __forceinline__ float soft_clamp_f(float x, float mn, float mx) {
    x = mx - softplus_fast(mx - x);
    x = mn + softplus_fast(x - mn);
    return x;
}

// ============================================================================
// Prep: pack weights into fp16 fragment order (unchanged, known-correct).
// ============================================================================
#define PREP_THREADS 164864   // 2576 slices * 64 lanes
__global__ __launch_bounds__(256) void prep_f16(
    const float* __restrict__ W0, const float* __restrict__ W1,
    const float* __restrict__ W2, const float* __restrict__ W3,
    const float* __restrict__ Wmu, const float* __restrict__ Wsg,
    unsigned short* __restrict__ ws)
{
    int t = blockIdx.x * 256 + threadIdx.x;
    if (t >= PREP_THREADS) return;
    int slice = t >> 6, l = t & 63;
    int l31 = l & 31, lg = l >> 5;
    const float* src; int e, nt, kt, Ksrc, N; bool head = false;
    if (slice < 224)       { int r = slice;      e=r>>5; r&=31;  nt=r>>2; kt=r&3;  src=W0; Ksrc=40;  N=256; }
    else if (slice < 1120) { int r = slice-224;  e=r>>7; r&=127; nt=r>>4; kt=r&15; src=W1; Ksrc=256; N=256; }
    else if (slice < 2016) { int r = slice-1120; e=r>>7; r&=127; nt=r>>4; kt=r&15; src=W2; Ksrc=256; N=256; }
    else if (slice < 2464) { int r = slice-2016; e=r>>6; r&=63;  nt=r>>4; kt=r&15; src=W3; Ksrc=256; N=128; }
    else                   { int r = slice-2464; e=r>>4; r&=15;  nt=r>>3; kt=r&7;
                             src = (nt==0) ? Wmu : Wsg; Ksrc=128; N=32; head=true; }
    int n  = head ? l31 : nt*32 + l31;
    int k0 = kt*16 + lg*8;
    f16x8 v;
    #pragma unroll
    for (int j = 0; j < 8; ++j) {
        int k = k0 + j;
        float x = (k < Ksrc) ? src[(e*Ksrc + k)*N + n] : 0.0f;
        v[j] = (f16)x;
    }
    *reinterpret_cast<f16x8*>(ws + (size_t)slice*512 + l*8) = v;
}

// ============================================================================
// Hidden layer, swapped operands: acc = mfma(W_frag, act_frag). (round-4 core)
// ============================================================================
template<int KT, int NTW, int ASTR, int SWZM>
__device__ __forceinline__ void layer_sw(
    const unsigned short* __restrict__ Wf, const float* __restrict__ bias,
    const unsigned short* __restrict__ aBuf, unsigned short* __restrict__ dBuf,
    int nt0, int lane)
{
    const int l31 = lane & 31, lg = lane >> 5;
    f32x16 acc[2][NTW];
    #pragma unroll
    for (int mt = 0; mt < 2; ++mt)
        #pragma unroll
        for (int jj = 0; jj < NTW; ++jj)
            #pragma unroll
            for (int r = 0; r < 16; ++r) acc[mt][jj][r] = 0.0f;

    const int ab0 = l31*ASTR, ab1 = (32 + l31)*ASTR;
    const int sw0 = l31 & SWZM, sw1 = (32 + l31) & SWZM;

    #pragma unroll
    for (int kt = 0; kt < KT; ++kt) {
        const int kg = kt*2 + lg;
        f16x8 w[NTW];
        #pragma unroll
        for (int jj = 0; jj < NTW; ++jj)
            w[jj] = *reinterpret_cast<const f16x8*>(Wf + (nt0+jj)*KT*512 + kt*512 + lane*8);
        f16x8 a0 = *reinterpret_cast<const f16x8*>(aBuf + ab0 + ((kg ^ sw0) << 3));
        f16x8 a1 = *reinterpret_cast<const f16x8*>(aBuf + ab1 + ((kg ^ sw1) << 3));
        #pragma unroll
        for (int jj = 0; jj < NTW; ++jj) {
            acc[0][jj] = __builtin_amdgcn_mfma_f32_32x32x16_f16(w[jj], a0, acc[0][jj], 0, 0, 0);
            acc[1][jj] = __builtin_amdgcn_mfma_f32_32x32x16_f16(w[jj], a1, acc[1][jj], 0, 0, 0);
        }
    }
    __syncthreads();   // all reads of aBuf complete -> safe to overwrite in place
    #pragma unroll
    for (int mt = 0; mt < 2; ++mt) {
        const int m  = mt*32 + l31;
        const int rb = m*256, swd = m & 15;
        #pragma unroll
        for (int jj = 0; jj < NTW; ++jj) {
            const int nb = (nt0+jj)*32 + 4*lg;
            #pragma unroll
            for (int g = 0; g < 4; ++g) {
                float4 bv = *reinterpret_cast<const float4*>(&bias[nb + 8*g]);
                f16x4 pk;
                pk[0] = (f16)swish_f(acc[mt][jj][4*g+0] + bv.x);
                pk[1] = (f16)swish_f(acc[mt][jj][4*g+1] + bv.y);
                pk[2] = (f16)swish_f(acc[mt][jj][4*g+2] + bv.z);
                pk[3] = (f16)swish_f(acc[mt][jj][4*g+3] + bv.w);
                const int cg = (nt0+jj)*4 + g;
                *reinterpret_cast<f16x4*>(dBuf + rb + ((cg ^ swd) << 3) + 4*lg) = pk;
            }
        }
    }
    __syncthreads();
}

// ============================================================================
// L0 direct-from-global: x-fragments built in registers (no xbuf, no staging).
// B-frag for (kt): lane l holds x[batch row l&31][k = kt*16 + (l>>5)*8 + j],
// i.e. 8 CONTIGUOUS floats of the row -> 2x float4 + cvt. kt=3 all-zero (skip).
// m-tile sequential to bound register pressure (~52 live).
// ============================================================================
template<int NTW>
__device__ __forceinline__ void layer0_direct(
    const unsigned short* __restrict__ Wf, const float* __restrict__ bias,
    const float* __restrict__ gs, const float* __restrict__ ga,
    unsigned short* __restrict__ dBuf, int brow0, int nt0, int lane)
{
    const int l31 = lane & 31, lg = lane >> 5;
    #pragma unroll
    for (int mt = 0; mt < 2; ++mt) {
        const int row = brow0 + mt*32 + l31;
        f16x8 xf[3];
        #pragma unroll
        for (int kt = 0; kt < 2; ++kt) {
            const float* p = &gs[(size_t)row*STATE_D + kt*16 + lg*8];
            float4 q0 = *reinterpret_cast<const float4*>(p);
            float4 q1 = *reinterpret_cast<const float4*>(p + 4);
            f16x8 v;
            v[0]=(f16)q0.x; v[1]=(f16)q0.y; v[2]=(f16)q0.z; v[3]=(f16)q0.w;
            v[4]=(f16)q1.x; v[5]=(f16)q1.y; v[6]=(f16)q1.z; v[7]=(f16)q1.w;
            xf[kt] = v;
        }
        {
            f16x8 v;
            if (lg == 0) {
                const float* p = &ga[(size_t)row*ACT_D];
                float4 q0 = *reinterpret_cast<const float4*>(p);
                float4 q1 = *reinterpret_cast<const float4*>(p + 4);
                v[0]=(f16)q0.x; v[1]=(f16)q0.y; v[2]=(f16)q0.z; v[3]=(f16)q0.w;
                v[4]=(f16)q1.x; v[5]=(f16)q1.y; v[6]=(f16)q1.z; v[7]=(f16)q1.w;
            } else {
                #pragma unroll
                for (int i = 0; i < 8; ++i) v[i] = (f16)0.0f;
            }
            xf[2] = v;
        }
        f32x16 acc[NTW];
        #pragma unroll
        for (int jj = 0; jj < NTW; ++jj)
            #pragma unroll
            for (int r = 0; r < 16; ++r) acc[jj][r] = 0.0f;
        #pragma unroll
        for (int kt = 0; kt < 3; ++kt) {     // kt=3 is zero-pad, skipped
            #pragma unroll
            for (int jj = 0; jj < NTW; ++jj) {
                f16x8 w = *reinterpret_cast<const f16x8*>(Wf + (nt0+jj)*4*512 + kt*512 + lane*8);
                acc[jj] = __builtin_amdgcn_mfma_f32_32x32x16_f16(w, xf[kt], acc[jj], 0, 0, 0);
            }
        }
        const int m  = mt*32 + l31;
        const int rb = m*256, swd = m & 15;
        #pragma unroll
        for (int jj = 0; jj < NTW; ++jj) {
            const int nb = (nt0+jj)*32 + 4*lg;
            #pragma unroll
            for (int g = 0; g < 4; ++g) {
                float4 bv = *reinterpret_cast<const float4*>(&bias[nb + 8*g]);
                f16x4 pk;
                pk[0] = (f16)swish_f(acc[jj][4*g+0] + bv.x);
                pk[1] = (f16)swish_f(acc[jj][4*g+1] + bv.y);
                pk[2] = (f16)swish_f(acc[jj][4*g+2] + bv.z);
                pk[3] = (f16)swish_f(acc[jj][4*g+3] + bv.w);
                const int cg = (nt0+jj)*4 + g;
                *reinterpret_cast<f16x4*>(dBuf + rb + ((cg ^ swd) << 3) + 4*lg) = pk;
            }
        }
    }
    __syncthreads();   // hbuf ready for L1
}

__global__ __launch_bounds__(256, 4) void ens16(
    const float* __restrict__ gs, const float* __restrict__ ga,
    const unsigned short* __restrict__ ws,
    const float* __restrict__ b0, const float* __restrict__ b1,
    const float* __restrict__ b2, const float* __restrict__ b3,
    const float* __restrict__ bmu, const float* __restrict__ bsg,
    const float* __restrict__ mxl, const float* __restrict__ mnl,
    float* __restrict__ out)
{
    __shared__ unsigned short hbuf[64*256];  // 32 KB -> 4 blocks/CU

    const int tid = threadIdx.x, lane = tid & 63, wv = tid >> 6;
    const int e = blockIdx.x >> 9;
    const int brow0 = (blockIdx.x & 511) << 6;

    // ---- layer chain ----
    layer0_direct<2>(ws + OFF_L0 + e*16384, b0 + e*256, gs, ga, hbuf, brow0, wv*2, lane);
    layer_sw<16,2, 256,15>(ws + OFF_L1 + e*65536, b1 + e*256, hbuf, hbuf, wv*2, lane);
    layer_sw<16,2, 256,15>(ws + OFF_L2 + e*65536, b2 + e*256, hbuf, hbuf, wv*2, lane);
    layer_sw<16,1, 256,15>(ws + OFF_L3 + e*32768, b3 + e*128, hbuf, hbuf, wv,   lane);

    // ---- heads (normal orientation): N=64 (mu|sig), K=128 ----
    {
        const unsigned short* WH = ws + OFF_H + e*8192;
        const int mt = wv >> 1, ntH = wv & 1;
        const int l31 = lane & 31, lg = lane >> 5;
        float bvH = (ntH == 0) ? bmu[e*32 + l31] : bsg[e*32 + l31];
        f32x16 acc;
        #pragma unroll
        for (int r = 0; r < 16; ++r) acc[r] = bvH;
        const unsigned short* wpH = WH + ntH*8*512 + lane*8;
        const int row0 = mt*32 + l31, ab = row0*256, sw = row0 & 15;
        #pragma unroll
        for (int kt = 0; kt < 8; ++kt) {
            int kg = kt*2 + lg;
            f16x8 ac = *reinterpret_cast<const f16x8*>(hbuf + ab + ((kg ^ sw) << 3));
            f16x8 bc = *reinterpret_cast<const f16x8*>(wpH + kt*512);
            acc = __builtin_amdgcn_mfma_f32_32x32x16_f16(ac, bc, acc, 0, 0, 0);
        }
        if (ntH == 0) {
            #pragma unroll
            for (int r = 0; r < 16; ++r) {
                int grow = brow0 + mt*32 + (r & 3) + 8*(r >> 2) + 4*lg;
                float v = acc[r] + gs[(size_t)grow*32 + l31];
                __builtin_nontemporal_store(v, &out[((size_t)e*BATCH + grow)*32 + l31]);
            }
        } else {
            float mx = mxl[l31], mn = mnl[l31];
            #pragma unroll
            for (int r = 0; r < 16; ++r) {
                int grow = brow0 + mt*32 + (r & 3) + 8*(r >> 2) + 4*lg;
                float v = __expf(soft_clamp_f(acc[r], mn, mx));
                __builtin_nontemporal_store(v,
                    &out[(size_t)E_N*BATCH*32 + ((size_t)e*BATCH + grow)*32 + l31]);
            }
        }
    }
}

// ============================================================================
// Fallback fp32 kernel (round-0, known-correct) in case ws is too small
// ============================================================================
#define TILE_B  64
#define THREADS 256
#define LDH     260
#define LDX     44
__device__ __forceinline__ float f4c(const float4& v, int i) {
    return reinterpret_cast<const float*>(&v)[i];
}
__device__ __forceinline__ float softplus_ref(float z) {
    return (z > 20.0f) ? z : log1pf(expf(z));
}
template<int K, int N, int LDIN, bool SW>
__device__ __forceinline__ void layer_fn(const float* __restrict__ lin,
                                         float* __restrict__ lout,
                                         const float* __restrict__ W,
                                         const float* __restrict__ bias,
                                         int tx, int ty)
{
    constexpr int CH = N / 64;
    float4 acc[4][CH];
    #pragma unroll
    for (int jj = 0; jj < CH; ++jj) {
        float4 bv = *reinterpret_cast<const float4*>(&bias[jj*64 + tx*4]);
        #pragma unroll
        for (int r = 0; r < 4; ++r) acc[r][jj] = bv;
    }
    for (int k0 = 0; k0 < K; k0 += 4) {
        float4 a[4];
        #pragma unroll
        for (int r = 0; r < 4; ++r)
            a[r] = *reinterpret_cast<const float4*>(&lin[(ty*4 + r)*LDIN + k0]);
        #pragma unroll
        for (int kk = 0; kk < 4; ++kk) {
            float4 w[CH];
            #pragma unroll
            for (int jj = 0; jj < CH; ++jj)
                w[jj] = *reinterpret_cast<const float4*>(&W[(k0+kk)*N + jj*64 + tx*4]);
            #pragma unroll
            for (int r = 0; r < 4; ++r) {
                float av = f4c(a[r], kk);
                #pragma unroll
                for (int jj = 0; jj < CH; ++jj) {
                    acc[r][jj].x = fmaf(av, w[jj].x, acc[r][jj].x);
                    acc[r][jj].y = fmaf(av, w[jj].y, acc[r][jj].y);
                    acc[r][jj].z = fmaf(av, w[jj].z, acc[r][jj].z);
                    acc[r][jj].w = fmaf(av, w[jj].w, acc[r][jj].w);
                }
            }
        }
    }
    __syncthreads();
    #pragma unroll
    for (int r = 0; r < 4; ++r) {
        #pragma unroll
        for (int jj = 0; jj < CH; ++jj) {
            float4 v = acc[r][jj];
            if (SW) { v.x = swish_f(v.x); v.y = swish_f(v.y); v.z = swish_f(v.z); v.w = swish_f(v.w); }
            *reinterpret_cast<float4*>(&lout[(ty*4 + r)*LDH + jj*64 + tx*4]) = v;
        }
    }
    __syncthreads();
}
__global__ __launch_bounds__(THREADS, 2)
void ens_fwd(const float* __restrict__ g_state, const float* __restrict__ g_action,
             const float* __restrict__ W0, const float* __restrict__ b0,
             const float* __restrict__ W1, const float* __restrict__ b1,
             const float* __restrict__ W2, const float* __restrict__ b2,
             const float* __restrict__ W3, const float* __restrict__ b3,
             const float* __restrict__ Wmu, const float* __restrict__ bmu,
             const float* __restrict__ Wsg, const float* __restrict__ bsg,
             const float* __restrict__ mxl, const float* __restrict__ mnl,
             float* __restrict__ out)
{
    __shared__ float h[TILE_B * LDH];
    __shared__ float xb[TILE_B * LDX];
    const int tid  = threadIdx.x;
    const int tx   = tid & 15;
    const int ty   = tid >> 4;
    const int e    = blockIdx.x / (BATCH / TILE_B);
    const int brow0 = (blockIdx.x % (BATCH / TILE_B)) * TILE_B;
    for (int i = tid; i < TILE_B * 8; i += THREADS) {
        int r = i >> 3, c = (i & 7) << 2;
        *reinterpret_cast<float4*>(&xb[r*LDX + c]) =
            *reinterpret_cast<const float4*>(&g_state[(size_t)(brow0 + r)*STATE_D + c]);
    }
    if (tid < TILE_B * 2) {
        int r = tid >> 1, c = (tid & 1) << 2;
        *reinterpret_cast<float4*>(&xb[r*LDX + STATE_D + c]) =
            *reinterpret_cast<const float4*>(&g_action[(size_t)(brow0 + r)*ACT_D + c]);
    }
    __syncthreads();
    layer_fn<40,  256, LDX, true>(xb, h, W0 + e*40*256,  b0 + e*256, tx, ty);
    layer_fn<256, 256, LDH, true>(h,  h, W1 + e*256*256, b1 + e*256, tx, ty);
    layer_fn<256, 256, LDH, true>(h,  h, W2 + e*256*256, b2 + e*256, tx, ty);
    layer_fn<256, 128, LDH, true>(h,  h, W3 + e*256*128, b3 + e*128, tx, ty);
    const float* Wm = Wmu + e*128*32;
    const float* Ws = Wsg + e*128*32;
    float2 am[4], as[4];
    {
        float2 bm = *reinterpret_cast<const float2*>(&bmu[e*32 + tx*2]);
        float2 bs = *reinterpret_cast<const float2*>(&bsg[e*32 + tx*2]);
        #pragma unroll
        for (int r = 0; r < 4; ++r) { am[r] = bm; as[r] = bs; }
    }
    for (int k0 = 0; k0 < 128; k0 += 4) {
        float4 a[4];
        #pragma unroll
        for (int r = 0; r < 4; ++r)
            a[r] = *reinterpret_cast<const float4*>(&h[(ty*4 + r)*LDH + k0]);
        #pragma unroll
        for (int kk = 0; kk < 4; ++kk) {
            float2 wm = *reinterpret_cast<const float2*>(&Wm[(k0+kk)*32 + tx*2]);
            float2 ws2 = *reinterpret_cast<const float2*>(&Ws[(k0+kk)*32 + tx*2]);
            #pragma unroll
            for (int r = 0; r < 4; ++r) {
                float av = f4c(a[r], kk);
                am[r].x = fmaf(av, wm.x, am[r].x);
                am[r].y = fmaf(av, wm.y, am[r].y);
                as[r].x = fmaf(av, ws2.x, as[r].x);
                as[r].y = fmaf(av, ws2.y, as[r].y);
            }
        }
    }
    const float2 mx = *reinterpret_cast<const float2*>(&mxl[tx*2]);
    const float2 mn = *reinterpret_cast<const float2*>(&mnl[tx*2]);
    #pragma unroll
    for (int r = 0; r < 4; ++r) {
        const int row = brow0 + ty*4 + r;
        float2 st = *reinterpret_cast<const float2*>(&g_state[(size_t)row*STATE_D + tx*2]);
        float2 mu; mu.x = am[r].x + st.x; mu.y = am[r].y + st.y;
        float2 sg;
        sg.x = expf(softplus_ref(fminf(as[r].x, 1e30f)) * 0.0f + (mx.x - softplus_ref(mx.x - as[r].x) >= mn.x
              ? mn.x + softplus_ref((mx.x - softplus_ref(mx.x - as[r].x)) - mn.x)
              : mn.x + softplus_ref((mx.x - softplus_ref(mx.x - as[r].x)) - mn.x)));
        sg.y = expf(mn.y + softplus_ref((mx.y - softplus_ref(mx.y - as[r].y)) - mn.y));
        size_t idx = ((size_t)e*BATCH + row)*DOUT + tx*2;
        *reinterpret_cast<float2*>(&out[idx]) = mu;
        *reinterpret_cast<float2*>(&out[(size_t)E_N*BATCH*DOUT + idx]) = sg;
    }
}

// ============================================================================
extern "C" void kernel_launch(void* const* d_in, const int* in_sizes, int n_in,
                              void* d_out, int out_size, void* d_ws, size_t ws_size,
                              hipStream_t stream) {
    (void)in_sizes; (void)n_in; (void)out_size;
    const float* state  = (const float*)d_in[0];
    const float* action = (const float*)d_in[1];
    const float* W0  = (const float*)d_in[2];
    const float* b0  = (const float*)d_in[3];
    const float* W1  = (const float*)d_in[4];
    const float* b1  = (const float*)d_in[5];
    const float* W2  = (const float*)d_in[6];
    const float* b2  = (const float*)d_in[7];
    const float* W3  = (const float*)d_in[8];
    const float* b3  = (const float*)d_in[9];
    const float* Wmu = (const float*)d_in[10];
    const float* bmu = (const float*)d_in[11];
    const float* Wsg = (const float*)d_in[12];
    const float* bsg = (const float*)d_in[13];
    const float* mxl = (const float*)d_in[14];
    const float* mnl = (const float*)d_in[15];
    float* out = (float*)d_out;

    if (ws_size >= WS_NEED) {
        unsigned short* ws = (unsigned short*)d_ws;
        prep_f16<<<dim3((PREP_THREADS + 255)/256), dim3(256), 0, stream>>>(
            W0, W1, W2, W3, Wmu, Wsg, ws);
        ens16<<<dim3(E_N * 512), dim3(256), 0, stream>>>(
            state, action, ws, b0, b1, b2, b3, bmu, bsg, mxl, mnl, out);
    } else {
        ens_fwd<<<dim3(E_N * (BATCH/TILE_B)), dim3(THREADS), 0, stream>>>(
            state, action, W0, b0, W1, b1, W2, b2, W3, b3,
            Wmu, bmu, Wsg, bsg, mxl, mnl, out);
    }
}

// Round 8
// 225.147 us; speedup vs baseline: 5.8861x; 1.1031x over previous
//
#include <hip/hip_runtime.h>
#include <math.h>
#include <stdint.h>

// ---------------- Problem constants ----------------
#define E_N     7
#define BATCH   32768
#define STATE_D 32
#define ACT_D   8
#define DOUT    32

typedef _Float16 f16;
typedef __attribute__((ext_vector_type(4)))  _Float16 f16x4;
typedef __attribute__((ext_vector_type(8)))  _Float16 f16x8;
typedef __attribute__((ext_vector_type(16))) float    f32x16;

// ---------------- ws layout (f16 elements), fragment-packed ----------------
// slice = one [64 lane][8 elem] fragment-tile group (512 f16 = 1KB)
// frag (nt,kt): lane l holds W[k = kt*16 + (l>>5)*8 + j][n = nt*32 + (l&31)]
// Serves as MFMA A-frag (row=n) or B-frag (col=n) identically.
#define OFF_L0  0           // e-stride 16384  (8nt*4kt*512)
#define OFF_L1  114688      // e-stride 65536  (8*16*512)
#define OFF_L2  573440
#define OFF_L3  1032192     // e-stride 32768  (4*16*512)
#define OFF_H   1261568     // e-stride 8192   (2*8*512)
#define WS_ELEMS 1318912
#define WS_NEED  ((size_t)WS_ELEMS*2)

// ---------------- fast math (hardware trans ops only, no libm) ----------------
__device__ __forceinline__ float swish_f(float x) {
    float t = __expf(-x);
    return x * __builtin_amdgcn_rcpf(1.0f + t);
}
__device__ __forceinline__ float softplus_fast(float z) {
    float sp = __logf(1.0f + __expf(z));   // z>88: inf -> select takes z
    return (z > 20.0f) ? z : sp;
}
__device__ __forceinline__ float soft_clamp_f(float x, float mn, float mx) {
    x = mx - softplus_fast(mx - x);
    x = mn + softplus_fast(x - mn);
    return x;
}

// ============================================================================
// Prep: pack weights into fp16 fragment order (unchanged, known-correct).
// ============================================================================
#define PREP_THREADS 164864   // 2576 slices * 64 lanes
__global__ __launch_bounds__(256) void prep_f16(
    const float* __restrict__ W0, const float* __restrict__ W1,
    const float* __restrict__ W2, const float* __restrict__ W3,
    const float* __restrict__ Wmu, const float* __restrict__ Wsg,
    unsigned short* __restrict__ ws)
{
    int t = blockIdx.x * 256 + threadIdx.x;
    if (t >= PREP_THREADS) return;
    int slice = t >> 6, l = t & 63;
    int l31 = l & 31, lg = l >> 5;
    const float* src; int e, nt, kt, Ksrc, N; bool head = false;
    if (slice < 224)       { int r = slice;      e=r>>5; r&=31;  nt=r>>2; kt=r&3;  src=W0; Ksrc=40;  N=256; }
    else if (slice < 1120) { int r = slice-224;  e=r>>7; r&=127; nt=r>>4; kt=r&15; src=W1; Ksrc=256; N=256; }
    else if (slice < 2016) { int r = slice-1120; e=r>>7; r&=127; nt=r>>4; kt=r&15; src=W2; Ksrc=256; N=256; }
    else if (slice < 2464) { int r = slice-2016; e=r>>6; r&=63;  nt=r>>4; kt=r&15; src=W3; Ksrc=256; N=128; }
    else                   { int r = slice-2464; e=r>>4; r&=15;  nt=r>>3; kt=r&7;
                             src = (nt==0) ? Wmu : Wsg; Ksrc=128; N=32; head=true; }
    int n  = head ? l31 : nt*32 + l31;
    int k0 = kt*16 + lg*8;
    f16x8 v;
    #pragma unroll
    for (int j = 0; j < 8; ++j) {
        int k = k0 + j;
        float x = (k < Ksrc) ? src[(e*Ksrc + k)*N + n] : 0.0f;
        v[j] = (f16)x;
    }
    *reinterpret_cast<f16x8*>(ws + (size_t)slice*512 + l*8) = v;
}

// ============================================================================
// Hidden layer, swapped operands: acc = mfma(W_frag, act_frag).
// ============================================================================
template<int KT, int NTW, int ASTR, int SWZM>
__device__ __forceinline__ void layer_sw(
    const unsigned short* __restrict__ Wf, const float* __restrict__ bias,
    const unsigned short* __restrict__ aBuf, unsigned short* __restrict__ dBuf,
    int nt0, int lane)
{
    const int l31 = lane & 31, lg = lane >> 5;
    f32x16 acc[2][NTW];
    #pragma unroll
    for (int mt = 0; mt < 2; ++mt)
        #pragma unroll
        for (int jj = 0; jj < NTW; ++jj)
            #pragma unroll
            for (int r = 0; r < 16; ++r) acc[mt][jj][r] = 0.0f;

    const int ab0 = l31*ASTR, ab1 = (32 + l31)*ASTR;
    const int sw0 = l31 & SWZM, sw1 = (32 + l31) & SWZM;

    #pragma unroll
    for (int kt = 0; kt < KT; ++kt) {
        const int kg = kt*2 + lg;
        f16x8 w[NTW];
        #pragma unroll
        for (int jj = 0; jj < NTW; ++jj)
            w[jj] = *reinterpret_cast<const f16x8*>(Wf + (nt0+jj)*KT*512 + kt*512 + lane*8);
        f16x8 a0 = *reinterpret_cast<const f16x8*>(aBuf + ab0 + ((kg ^ sw0) << 3));
        f16x8 a1 = *reinterpret_cast<const f16x8*>(aBuf + ab1 + ((kg ^ sw1) << 3));
        #pragma unroll
        for (int jj = 0; jj < NTW; ++jj) {
            acc[0][jj] = __builtin_amdgcn_mfma_f32_32x32x16_f16(w[jj], a0, acc[0][jj], 0, 0, 0);
            acc[1][jj] = __builtin_amdgcn_mfma_f32_32x32x16_f16(w[jj], a1, acc[1][jj], 0, 0, 0);
        }
    }
    __syncthreads();   // all reads of aBuf complete -> safe to overwrite in place
    #pragma unroll
    for (int mt = 0; mt < 2; ++mt) {
        const int m  = mt*32 + l31;
        const int rb = m*256, swd = m & 15;
        #pragma unroll
        for (int jj = 0; jj < NTW; ++jj) {
            const int nb = (nt0+jj)*32 + 4*lg;
            #pragma unroll
            for (int g = 0; g < 4; ++g) {
                float4 bv = *reinterpret_cast<const float4*>(&bias[nb + 8*g]);
                f16x4 pk;
                pk[0] = (f16)swish_f(acc[mt][jj][4*g+0] + bv.x);
                pk[1] = (f16)swish_f(acc[mt][jj][4*g+1] + bv.y);
                pk[2] = (f16)swish_f(acc[mt][jj][4*g+2] + bv.z);
                pk[3] = (f16)swish_f(acc[mt][jj][4*g+3] + bv.w);
                const int cg = (nt0+jj)*4 + g;
                *reinterpret_cast<f16x4*>(dBuf + rb + ((cg ^ swd) << 3) + 4*lg) = pk;
            }
        }
    }
    __syncthreads();
}

// ============================================================================
// L0 direct-from-global: x-fragments built in registers (no xbuf, no staging).
// ============================================================================
template<int NTW>
__device__ __forceinline__ void layer0_direct(
    const unsigned short* __restrict__ Wf, const float* __restrict__ bias,
    const float* __restrict__ gs, const float* __restrict__ ga,
    unsigned short* __restrict__ dBuf, int brow0, int nt0, int lane)
{
    const int l31 = lane & 31, lg = lane >> 5;
    #pragma unroll
    for (int mt = 0; mt < 2; ++mt) {
        const int row = brow0 + mt*32 + l31;
        f16x8 xf[3];
        #pragma unroll
        for (int kt = 0; kt < 2; ++kt) {
            const float* p = &gs[(size_t)row*STATE_D + kt*16 + lg*8];
            float4 q0 = *reinterpret_cast<const float4*>(p);
            float4 q1 = *reinterpret_cast<const float4*>(p + 4);
            f16x8 v;
            v[0]=(f16)q0.x; v[1]=(f16)q0.y; v[2]=(f16)q0.z; v[3]=(f16)q0.w;
            v[4]=(f16)q1.x; v[5]=(f16)q1.y; v[6]=(f16)q1.z; v[7]=(f16)q1.w;
            xf[kt] = v;
        }
        {
            f16x8 v;
            if (lg == 0) {
                const float* p = &ga[(size_t)row*ACT_D];
                float4 q0 = *reinterpret_cast<const float4*>(p);
                float4 q1 = *reinterpret_cast<const float4*>(p + 4);
                v[0]=(f16)q0.x; v[1]=(f16)q0.y; v[2]=(f16)q0.z; v[3]=(f16)q0.w;
                v[4]=(f16)q1.x; v[5]=(f16)q1.y; v[6]=(f16)q1.z; v[7]=(f16)q1.w;
            } else {
                #pragma unroll
                for (int i = 0; i < 8; ++i) v[i] = (f16)0.0f;
            }
            xf[2] = v;
        }
        f32x16 acc[NTW];
        #pragma unroll
        for (int jj = 0; jj < NTW; ++jj)
            #pragma unroll
            for (int r = 0; r < 16; ++r) acc[jj][r] = 0.0f;
        #pragma unroll
        for (int kt = 0; kt < 3; ++kt) {     // kt=3 is zero-pad, skipped
            #pragma unroll
            for (int jj = 0; jj < NTW; ++jj) {
                f16x8 w = *reinterpret_cast<const f16x8*>(Wf + (nt0+jj)*4*512 + kt*512 + lane*8);
                acc[jj] = __builtin_amdgcn_mfma_f32_32x32x16_f16(w, xf[kt], acc[jj], 0, 0, 0);
            }
        }
        const int m  = mt*32 + l31;
        const int rb = m*256, swd = m & 15;
        #pragma unroll
        for (int jj = 0; jj < NTW; ++jj) {
            const int nb = (nt0+jj)*32 + 4*lg;
            #pragma unroll
            for (int g = 0; g < 4; ++g) {
                float4 bv = *reinterpret_cast<const float4*>(&bias[nb + 8*g]);
                f16x4 pk;
                pk[0] = (f16)swish_f(acc[jj][4*g+0] + bv.x);
                pk[1] = (f16)swish_f(acc[jj][4*g+1] + bv.y);
                pk[2] = (f16)swish_f(acc[jj][4*g+2] + bv.z);
                pk[3] = (f16)swish_f(acc[jj][4*g+3] + bv.w);
                const int cg = (nt0+jj)*4 + g;
                *reinterpret_cast<f16x4*>(dBuf + rb + ((cg ^ swd) << 3) + 4*lg) = pk;
            }
        }
    }
    __syncthreads();   // hbuf ready for L1
}

// launch_bounds(256,3): 3 waves/EU -> ~170 unified regs/wave. acc (64 AGPR)
// + ~100 arch VGPR fits WITHOUT spill, and gives the scheduler room to hoist
// W-loads across the unrolled K-loop. (256,4) = 128 regs/wave pinned arch
// VGPRs at 64 and spilled the rest (rounds 3-5: pinned VGPR_Count=64,
// WRITE_SIZE 3x output). Observed occupancy was already ~3 blocks/CU.
__global__ __launch_bounds__(256, 3) void ens16(
    const float* __restrict__ gs, const float* __restrict__ ga,
    const unsigned short* __restrict__ ws,
    const float* __restrict__ b0, const float* __restrict__ b1,
    const float* __restrict__ b2, const float* __restrict__ b3,
    const float* __restrict__ bmu, const float* __restrict__ bsg,
    const float* __restrict__ mxl, const float* __restrict__ mnl,
    float* __restrict__ out)
{
    __shared__ unsigned short hbuf[64*256];  // 32 KB

    const int tid = threadIdx.x, lane = tid & 63, wv = tid >> 6;
    const int e = blockIdx.x >> 9;
    const int brow0 = (blockIdx.x & 511) << 6;

    // ---- layer chain ----
    layer0_direct<2>(ws + OFF_L0 + e*16384, b0 + e*256, gs, ga, hbuf, brow0, wv*2, lane);
    layer_sw<16,2, 256,15>(ws + OFF_L1 + e*65536, b1 + e*256, hbuf, hbuf, wv*2, lane);
    layer_sw<16,2, 256,15>(ws + OFF_L2 + e*65536, b2 + e*256, hbuf, hbuf, wv*2, lane);
    layer_sw<16,1, 256,15>(ws + OFF_L3 + e*32768, b3 + e*128, hbuf, hbuf, wv,   lane);

    // ---- heads (normal orientation): N=64 (mu|sig), K=128 ----
    {
        const unsigned short* WH = ws + OFF_H + e*8192;
        const int mt = wv >> 1, ntH = wv & 1;
        const int l31 = lane & 31, lg = lane >> 5;
        float bvH = (ntH == 0) ? bmu[e*32 + l31] : bsg[e*32 + l31];
        f32x16 acc;
        #pragma unroll
        for (int r = 0; r < 16; ++r) acc[r] = bvH;
        const unsigned short* wpH = WH + ntH*8*512 + lane*8;
        const int row0 = mt*32 + l31, ab = row0*256, sw = row0 & 15;
        #pragma unroll
        for (int kt = 0; kt < 8; ++kt) {
            int kg = kt*2 + lg;
            f16x8 ac = *reinterpret_cast<const f16x8*>(hbuf + ab + ((kg ^ sw) << 3));
            f16x8 bc = *reinterpret_cast<const f16x8*>(wpH + kt*512);
            acc = __builtin_amdgcn_mfma_f32_32x32x16_f16(ac, bc, acc, 0, 0, 0);
        }
        if (ntH == 0) {
            #pragma unroll
            for (int r = 0; r < 16; ++r) {
                int grow = brow0 + mt*32 + (r & 3) + 8*(r >> 2) + 4*lg;
                float v = acc[r] + gs[(size_t)grow*32 + l31];
                __builtin_nontemporal_store(v, &out[((size_t)e*BATCH + grow)*32 + l31]);
            }
        } else {
            float mx = mxl[l31], mn = mnl[l31];
            #pragma unroll
            for (int r = 0; r < 16; ++r) {
                int grow = brow0 + mt*32 + (r & 3) + 8*(r >> 2) + 4*lg;
                float v = __expf(soft_clamp_f(acc[r], mn, mx));
                __builtin_nontemporal_store(v,
                    &out[(size_t)E_N*BATCH*32 + ((size_t)e*BATCH + grow)*32 + l31]);
            }
        }
    }
}

// ============================================================================
// Fallback fp32 kernel (round-0, known-correct) in case ws is too small
// ============================================================================
#define TILE_B  64
#define THREADS 256
#define LDH     260
#define LDX     44
__device__ __forceinline__ float f4c(const float4& v, int i) {
    return reinterpret_cast<const float*>(&v)[i];
}
__device__ __forceinline__ float softplus_ref(float z) {
    return (z > 20.0f) ? z : log1pf(expf(z));
}
__device__ __forceinline__ float soft_clamp_ref(float x, float mn, float mx) {
    x = mx - softplus_ref(mx - x);
    x = mn + softplus_ref(x - mn);
    return x;
}
template<int K, int N, int LDIN, bool SW>
__device__ __forceinline__ void layer_fn(const float* __restrict__ lin,
                                         float* __restrict__ lout,
                                         const float* __restrict__ W,
                                         const float* __restrict__ bias,
                                         int tx, int ty)
{
    constexpr int CH = N / 64;
    float4 acc[4][CH];
    #pragma unroll
    for (int jj = 0; jj < CH; ++jj) {
        float4 bv = *reinterpret_cast<const float4*>(&bias[jj*64 + tx*4]);
        #pragma unroll
        for (int r = 0; r < 4; ++r) acc[r][jj] = bv;
    }
    for (int k0 = 0; k0 < K; k0 += 4) {
        float4 a[4];
        #pragma unroll
        for (int r = 0; r < 4; ++r)
            a[r] = *reinterpret_cast<const float4*>(&lin[(ty*4 + r)*LDIN + k0]);
        #pragma unroll
        for (int kk = 0; kk < 4; ++kk) {
            float4 w[CH];
            #pragma unroll
            for (int jj = 0; jj < CH; ++jj)
                w[jj] = *reinterpret_cast<const float4*>(&W[(k0+kk)*N + jj*64 + tx*4]);
            #pragma unroll
            for (int r = 0; r < 4; ++r) {
                float av = f4c(a[r], kk);
                #pragma unroll
                for (int jj = 0; jj < CH; ++jj) {
                    acc[r][jj].x = fmaf(av, w[jj].x, acc[r][jj].x);
                    acc[r][jj].y = fmaf(av, w[jj].y, acc[r][jj].y);
                    acc[r][jj].z = fmaf(av, w[jj].z, acc[r][jj].z);
                    acc[r][jj].w = fmaf(av, w[jj].w, acc[r][jj].w);
                }
            }
        }
    }
    __syncthreads();
    #pragma unroll
    for (int r = 0; r < 4; ++r) {
        #pragma unroll
        for (int jj = 0; jj < CH; ++jj) {
            float4 v = acc[r][jj];
            if (SW) { v.x = swish_f(v.x); v.y = swish_f(v.y); v.z = swish_f(v.z); v.w = swish_f(v.w); }
            *reinterpret_cast<float4*>(&lout[(ty*4 + r)*LDH + jj*64 + tx*4]) = v;
        }
    }
    __syncthreads();
}
__global__ __launch_bounds__(THREADS, 2)
void ens_fwd(const float* __restrict__ g_state, const float* __restrict__ g_action,
             const float* __restrict__ W0, const float* __restrict__ b0,
             const float* __restrict__ W1, const float* __restrict__ b1,
             const float* __restrict__ W2, const float* __restrict__ b2,
             const float* __restrict__ W3, const float* __restrict__ b3,
             const float* __restrict__ Wmu, const float* __restrict__ bmu,
             const float* __restrict__ Wsg, const float* __restrict__ bsg,
             const float* __restrict__ mxl, const float* __restrict__ mnl,
             float* __restrict__ out)
{
    __shared__ float h[TILE_B * LDH];
    __shared__ float xb[TILE_B * LDX];
    const int tid  = threadIdx.x;
    const int tx   = tid & 15;
    const int ty   = tid >> 4;
    const int e    = blockIdx.x / (BATCH / TILE_B);
    const int brow0 = (blockIdx.x % (BATCH / TILE_B)) * TILE_B;
    for (int i = tid; i < TILE_B * 8; i += THREADS) {
        int r = i >> 3, c = (i & 7) << 2;
        *reinterpret_cast<float4*>(&xb[r*LDX + c]) =
            *reinterpret_cast<const float4*>(&g_state[(size_t)(brow0 + r)*STATE_D + c]);
    }
    if (tid < TILE_B * 2) {
        int r = tid >> 1, c = (tid & 1) << 2;
        *reinterpret_cast<float4*>(&xb[r*LDX + STATE_D + c]) =
            *reinterpret_cast<const float4*>(&g_action[(size_t)(brow0 + r)*ACT_D + c]);
    }
    __syncthreads();
    layer_fn<40,  256, LDX, true>(xb, h, W0 + e*40*256,  b0 + e*256, tx, ty);
    layer_fn<256, 256, LDH, true>(h,  h, W1 + e*256*256, b1 + e*256, tx, ty);
    layer_fn<256, 256, LDH, true>(h,  h, W2 + e*256*256, b2 + e*256, tx, ty);
    layer_fn<256, 128, LDH, true>(h,  h, W3 + e*256*128, b3 + e*128, tx, ty);
    const float* Wm = Wmu + e*128*32;
    const float* Ws = Wsg + e*128*32;
    float2 am[4], as[4];
    {
        float2 bm = *reinterpret_cast<const float2*>(&bmu[e*32 + tx*2]);
        float2 bs = *reinterpret_cast<const float2*>(&bsg[e*32 + tx*2]);
        #pragma unroll
        for (int r = 0; r < 4; ++r) { am[r] = bm; as[r] = bs; }
    }
    for (int k0 = 0; k0 < 128; k0 += 4) {
        float4 a[4];
        #pragma unroll
        for (int r = 0; r < 4; ++r)
            a[r] = *reinterpret_cast<const float4*>(&h[(ty*4 + r)*LDH + k0]);
        #pragma unroll
        for (int kk = 0; kk < 4; ++kk) {
            float2 wm = *reinterpret_cast<const float2*>(&Wm[(k0+kk)*32 + tx*2]);
            float2 ws2 = *reinterpret_cast<const float2*>(&Ws[(k0+kk)*32 + tx*2]);
            #pragma unroll
            for (int r = 0; r < 4; ++r) {
                float av = f4c(a[r], kk);
                am[r].x = fmaf(av, wm.x, am[r].x);
                am[r].y = fmaf(av, wm.y, am[r].y);
                as[r].x = fmaf(av, ws2.x, as[r].x);
                as[r].y = fmaf(av, ws2.y, as[r].y);
            }
        }
    }
    const float2 mx = *reinterpret_cast<const float2*>(&mxl[tx*2]);
    const float2 mn = *reinterpret_cast<const float2*>(&mnl[tx*2]);
    #pragma unroll
    for (int r = 0; r < 4; ++r) {
        const int row = brow0 + ty*4 + r;
        float2 st = *reinterpret_cast<const float2*>(&g_state[(size_t)row*STATE_D + tx*2]);
        float2 mu; mu.x = am[r].x + st.x; mu.y = am[r].y + st.y;
        float2 sg;
        sg.x = expf(soft_clamp_ref(as[r].x, mn.x, mx.x));
        sg.y = expf(soft_clamp_ref(as[r].y, mn.y, mx.y));
        size_t idx = ((size_t)e*BATCH + row)*DOUT + tx*2;
        *reinterpret_cast<float2*>(&out[idx]) = mu;
        *reinterpret_cast<float2*>(&out[(size_t)E_N*BATCH*DOUT + idx]) = sg;
    }
}

// ============================================================================
extern "C" void kernel_launch(void* const* d_in, const int* in_sizes, int n_in,
                              void* d_out, int out_size, void* d_ws, size_t ws_size,
                              hipStream_t stream) {
    (void)in_sizes; (void)n_in; (void)out_size;
    const float* state  = (const float*)d_in[0];
    const float* action = (const float*)d_in[1];
    const float* W0  = (const float*)d_in[2];
    const float* b0  = (const float*)d_in[3];
    const float* W1  = (const float*)d_in[4];
    const float* b1  = (const float*)d_in[5];
    const float* W2  = (const float*)d_in[6];
    const float* b2  = (const float*)d_in[7];
    const float* W3  = (const float*)d_in[8];
    const float* b3  = (const float*)d_in[9];
    const float* Wmu = (const float*)d_in[10];
    const float* bmu = (const float*)d_in[11];
    const float* Wsg = (const float*)d_in[12];
    const float* bsg = (const float*)d_in[13];
    const float* mxl = (const float*)d_in[14];
    const float* mnl = (const float*)d_in[15];
    float* out = (float*)d_out;

    if (ws_size >= WS_NEED) {
        unsigned short* ws = (unsigned short*)d_ws;
        prep_f16<<<dim3((PREP_THREADS + 255)/256), dim3(256), 0, stream>>>(
            W0, W1, W2, W3, Wmu, Wsg, ws);
        ens16<<<dim3(E_N * 512), dim3(256), 0, stream>>>(
            state, action, ws, b0, b1, b2, b3, bmu, bsg, mxl, mnl, out);
    } else {
        ens_fwd<<<dim3(E_N * (BATCH/TILE_B)), dim3(THREADS), 0, stream>>>(
            state, action, W0, b0, W1, b1, W2, b2, W3, b3,
            Wmu, bmu, Wsg, bsg, mxl, mnl, out);
    }
}